// Round 1
// baseline (1759.282 us; speedup 1.0000x reference)
//
#include <hip/hip_runtime.h>
#include <math.h>

#define THREADS 256

// ---------------- CSR build ----------------

__global__ void k_deg(const int* __restrict__ dst, int* __restrict__ deg, int E) {
  int e = blockIdx.x * blockDim.x + threadIdx.x;
  if (e < E) atomicAdd(&deg[dst[e]], 1);
}

// single-block chunked exclusive scan: deg[0..n) -> row_ptr[0..n]
__global__ void k_scan(const int* __restrict__ deg, int* __restrict__ row_ptr, int n) {
  __shared__ int sums[1024];
  int t = threadIdx.x;
  int chunk = (n + 1023) >> 10;
  int begin = t * chunk;
  int end = min(begin + chunk, n);
  int s = 0;
  for (int i = begin; i < end; ++i) s += deg[i];
  sums[t] = s;
  __syncthreads();
  for (int off = 1; off < 1024; off <<= 1) {
    int v = (t >= off) ? sums[t - off] : 0;
    __syncthreads();
    if (t >= off) sums[t] += v;
    __syncthreads();
  }
  int run = sums[t] - s;  // exclusive prefix of this chunk
  for (int i = begin; i < end; ++i) { row_ptr[i] = run; run += deg[i]; }
  if (end == n) row_ptr[n] = run;
}

__global__ void k_fill(const int* __restrict__ src, const int* __restrict__ dst,
                       const int* __restrict__ row_ptr, int* __restrict__ cursor,
                       int* __restrict__ col, int E) {
  int e = blockIdx.x * blockDim.x + threadIdx.x;
  if (e < E) {
    int d = dst[e];
    int p = atomicAdd(&cursor[d], 1);
    col[row_ptr[d] + p] = src[e];
  }
}

// ---------------- dual GEMM, D=128 ----------------
// outL = X@Wl ; outR = X@Wr + b   (X:[M,128], W:[128,128] row-major)
// blockIdx.y selects side. BM=64 rows/block, 256 threads, 4x8 register tile.
__global__ __launch_bounds__(256) void dual_gemm128(
    const float* __restrict__ X, const float* __restrict__ Wl,
    const float* __restrict__ Wr, const float* __restrict__ b,
    float* __restrict__ outL, float* __restrict__ outR, int M) {
  __shared__ float Xs[128 * 64];  // [k][r], 32KB (transposed X tile)
  __shared__ float Ws[32 * 128];  // [k][c] chunk, 16KB
  const float* W = blockIdx.y ? Wr : Wl;
  float* out = blockIdx.y ? outR : outL;
  int row0 = blockIdx.x * 64;
  int tid = threadIdx.x;

  // stage X tile transposed (one-time, conflicts amortized)
  {
    int rbase = tid >> 5;       // 0..7
    int kq = tid & 31;          // float4 index along k
    for (int rr = rbase; rr < 64; rr += 8) {
      int row = row0 + rr;
      float4 v = make_float4(0.f, 0.f, 0.f, 0.f);
      if (row < M) v = ((const float4*)(X + (size_t)row * 128))[kq];
      int k = kq * 4;
      Xs[(k + 0) * 64 + rr] = v.x;
      Xs[(k + 1) * 64 + rr] = v.y;
      Xs[(k + 2) * 64 + rr] = v.z;
      Xs[(k + 3) * 64 + rr] = v.w;
    }
  }

  float acc[4][8];
#pragma unroll
  for (int i = 0; i < 4; ++i)
#pragma unroll
    for (int j = 0; j < 8; ++j) acc[i][j] = 0.f;

  int tx = tid & 15, ty = tid >> 4;
  int r0 = ty * 4;
  int c0 = tx * 4;  // cols c0..c0+3 and c0+64..c0+67 (2-way LDS alias = free)

  for (int kk = 0; kk < 128; kk += 32) {
    __syncthreads();  // protects Xs (first iter) and Ws reuse
    for (int i = tid; i < 1024; i += 256) {  // 1024 float4s = 32x128 chunk
      int k = i >> 5, cq = i & 31;
      ((float4*)Ws)[i] = ((const float4*)(W + (size_t)(kk + k) * 128))[cq];
    }
    __syncthreads();
#pragma unroll
    for (int k = 0; k < 32; ++k) {
      const float4 xv = *(const float4*)&Xs[(kk + k) * 64 + r0];
      const float4 wa = *(const float4*)&Ws[k * 128 + c0];
      const float4 wb = *(const float4*)&Ws[k * 128 + c0 + 64];
      float xf[4] = {xv.x, xv.y, xv.z, xv.w};
      float wf[8] = {wa.x, wa.y, wa.z, wa.w, wb.x, wb.y, wb.z, wb.w};
#pragma unroll
      for (int i = 0; i < 4; ++i)
#pragma unroll
        for (int j = 0; j < 8; ++j) acc[i][j] = fmaf(xf[i], wf[j], acc[i][j]);
    }
  }

  float bl[8] = {0.f, 0.f, 0.f, 0.f, 0.f, 0.f, 0.f, 0.f};
  if (blockIdx.y) {
#pragma unroll
    for (int j = 0; j < 4; ++j) { bl[j] = b[c0 + j]; bl[4 + j] = b[c0 + 64 + j]; }
  }
#pragma unroll
  for (int i = 0; i < 4; ++i) {
    int row = row0 + r0 + i;
    if (row >= M) continue;
    float4 o0, o1;
    o0.x = acc[i][0] + bl[0]; o0.y = acc[i][1] + bl[1];
    o0.z = acc[i][2] + bl[2]; o0.w = acc[i][3] + bl[3];
    o1.x = acc[i][4] + bl[4]; o1.y = acc[i][5] + bl[5];
    o1.z = acc[i][6] + bl[6]; o1.w = acc[i][7] + bl[7];
    *(float4*)&out[(size_t)row * 128 + c0] = o0;
    *(float4*)&out[(size_t)row * 128 + c0 + 64] = o1;
  }
}

// ---------------- dual GEMM, D=40 (layer 2) ----------------
// outL = X@Wl ; outR = X@Wr + b   (W:[128,40]); thread = 1 col x 4 rows
__global__ __launch_bounds__(256) void dual_gemm40(
    const float* __restrict__ X, const float* __restrict__ Wl,
    const float* __restrict__ Wr, const float* __restrict__ b,
    float* __restrict__ outL, float* __restrict__ outR, int M) {
  __shared__ float Ws[128 * 80];  // [k][c80]: c<40 -> Wl, else Wr
  for (int i = threadIdx.x; i < 128 * 80; i += 256) {
    int k = i / 80, c = i - k * 80;
    Ws[i] = (c < 40) ? Wl[k * 40 + c] : Wr[k * 40 + (c - 40)];
  }
  __syncthreads();
  int g = blockIdx.x * 256 + threadIdx.x;
  int rgroups = (M + 3) >> 2;
  if (g >= rgroups * 80) return;
  int c80 = g % 80;
  int r0 = (g / 80) * 4;
  const float* xp0 = X + (size_t)min(r0 + 0, M - 1) * 128;
  const float* xp1 = X + (size_t)min(r0 + 1, M - 1) * 128;
  const float* xp2 = X + (size_t)min(r0 + 2, M - 1) * 128;
  const float* xp3 = X + (size_t)min(r0 + 3, M - 1) * 128;
  float acc[4] = {0.f, 0.f, 0.f, 0.f};
#pragma unroll
  for (int k = 0; k < 128; k += 4) {
    float4 a0 = *(const float4*)(xp0 + k);
    float4 a1 = *(const float4*)(xp1 + k);
    float4 a2 = *(const float4*)(xp2 + k);
    float4 a3 = *(const float4*)(xp3 + k);
    float w0 = Ws[(k + 0) * 80 + c80];
    float w1 = Ws[(k + 1) * 80 + c80];
    float w2 = Ws[(k + 2) * 80 + c80];
    float w3 = Ws[(k + 3) * 80 + c80];
    acc[0] = fmaf(a0.x, w0, fmaf(a0.y, w1, fmaf(a0.z, w2, fmaf(a0.w, w3, acc[0]))));
    acc[1] = fmaf(a1.x, w0, fmaf(a1.y, w1, fmaf(a1.z, w2, fmaf(a1.w, w3, acc[1]))));
    acc[2] = fmaf(a2.x, w0, fmaf(a2.y, w1, fmaf(a2.z, w2, fmaf(a2.w, w3, acc[2]))));
    acc[3] = fmaf(a3.x, w0, fmaf(a3.y, w1, fmaf(a3.z, w2, fmaf(a3.w, w3, acc[3]))));
  }
  bool right = c80 >= 40;
  int c = right ? (c80 - 40) : c80;
  float bias = right ? b[c] : 0.f;
  float* out = right ? outR : outL;
#pragma unroll
  for (int i = 0; i < 4; ++i) {
    int row = r0 + i;
    if (row < M) out[(size_t)row * 40 + c] = acc[i] + bias;
  }
}

// ---------------- aggregation D=128, fused deg_inv + add + relu ----------------
// h[n] = relu(deg_inv[n] * sum_{e in CSR(n)} xl[col[e]] + xr[n])
__global__ __launch_bounds__(256) void agg128_relu(
    const float* __restrict__ xl, const float* __restrict__ xr,
    const int* __restrict__ row_ptr, const int* __restrict__ col,
    float* __restrict__ h, int Nn) {
  int wave = threadIdx.x >> 6;
  int lane = threadIdx.x & 63;
  int n = blockIdx.x * 4 + wave;
  if (n >= Nn) return;
  int beg = row_ptr[n], end = row_ptr[n + 1];
  const float2* xl2 = (const float2*)xl;
  float ax = 0.f, ay = 0.f;
  int e = beg;
  for (; e + 2 <= end; e += 2) {
    int s0 = col[e], s1 = col[e + 1];
    float2 v0 = xl2[(size_t)s0 * 64 + lane];
    float2 v1 = xl2[(size_t)s1 * 64 + lane];
    ax += v0.x + v1.x;
    ay += v0.y + v1.y;
  }
  if (e < end) {
    int s0 = col[e];
    float2 v0 = xl2[(size_t)s0 * 64 + lane];
    ax += v0.x; ay += v0.y;
  }
  float di = 1.0f / (float)max(end - beg, 1);
  float2 rv = ((const float2*)xr)[(size_t)n * 64 + lane];
  float2 o;
  o.x = fmaxf(fmaf(ax, di, rv.x), 0.f);
  o.y = fmaxf(fmaf(ay, di, rv.y), 0.f);
  ((float2*)h)[(size_t)n * 64 + lane] = o;
}

// ---------------- aggregation D=40, fused deg_inv + add + log_softmax ----------------
__global__ __launch_bounds__(256) void agg40_lsm(
    const float* __restrict__ tl, const float* __restrict__ tr,
    const int* __restrict__ row_ptr, const int* __restrict__ col,
    float* __restrict__ out, int Nn) {
  int wave = threadIdx.x >> 6;
  int lane = threadIdx.x & 63;
  int n = blockIdx.x * 4 + wave;
  if (n >= Nn) return;
  int beg = row_ptr[n], end = row_ptr[n + 1];
  bool active = lane < 40;
  int li = active ? lane : 0;
  float acc = 0.f;
  int e = beg;
  for (; e + 2 <= end; e += 2) {
    int s0 = col[e], s1 = col[e + 1];
    acc += tl[(size_t)s0 * 40 + li] + tl[(size_t)s1 * 40 + li];
  }
  if (e < end) acc += tl[(size_t)col[e] * 40 + li];
  float di = 1.0f / (float)max(end - beg, 1);
  float v = active ? fmaf(acc, di, tr[(size_t)n * 40 + lane]) : -INFINITY;
  float m = v;
#pragma unroll
  for (int off = 32; off; off >>= 1) m = fmaxf(m, __shfl_xor(m, off));
  float ex = active ? expf(v - m) : 0.f;
  float ssum = ex;
#pragma unroll
  for (int off = 32; off; off >>= 1) ssum += __shfl_xor(ssum, off);
  if (active) out[(size_t)n * 40 + lane] = (v - m) - logf(ssum);
}

// ---------------- launcher ----------------

extern "C" void kernel_launch(void* const* d_in, const int* in_sizes, int n_in,
                              void* d_out, int out_size, void* d_ws, size_t ws_size,
                              hipStream_t stream) {
  const float* x   = (const float*)d_in[0];
  const int*   ei  = (const int*)d_in[1];
  const float* Wl0 = (const float*)d_in[2];
  const float* Wr0 = (const float*)d_in[3];
  const float* b0  = (const float*)d_in[4];
  const float* Wl1 = (const float*)d_in[5];
  const float* Wr1 = (const float*)d_in[6];
  const float* b1  = (const float*)d_in[7];
  const float* Wl2 = (const float*)d_in[8];
  const float* Wr2 = (const float*)d_in[9];
  const float* b2  = (const float*)d_in[10];

  int N = in_sizes[0] / 128;
  int E = in_sizes[1] / 2;
  const int* src = ei;
  const int* dst = ei + E;

  char* ws = (char*)d_ws;
  size_t off = 0;
  auto alloc = [&](size_t bytes) -> void* {
    void* p = ws + off;
    off += (bytes + 255) & ~(size_t)255;
    return p;
  };
  float* bufA   = (float*)alloc((size_t)N * 128 * 4);
  float* bufB   = (float*)alloc((size_t)N * 128 * 4);
  float* bufC   = (float*)alloc((size_t)N * 128 * 4);
  int* row_ptr  = (int*)alloc((size_t)(N + 1) * 4);
  int* deg      = (int*)alloc((size_t)N * 4);
  int* cursor   = (int*)alloc((size_t)N * 4);
  int* col      = (int*)alloc((size_t)E * 4);
  (void)ws_size; (void)n_in; (void)out_size;

  hipMemsetAsync(deg, 0, (size_t)N * 4, stream);
  hipMemsetAsync(cursor, 0, (size_t)N * 4, stream);

  int eb = (E + THREADS - 1) / THREADS;
  k_deg<<<eb, THREADS, 0, stream>>>(dst, deg, E);
  k_scan<<<1, 1024, 0, stream>>>(deg, row_ptr, N);
  k_fill<<<eb, THREADS, 0, stream>>>(src, dst, row_ptr, cursor, col, E);

  dim3 gg((N + 63) / 64, 2);
  int nb = (N + 3) / 4;

  // layer 0
  dual_gemm128<<<gg, 256, 0, stream>>>(x, Wl0, Wr0, b0, bufA, bufB, N);
  agg128_relu<<<nb, 256, 0, stream>>>(bufA, bufB, row_ptr, col, bufC, N);
  // layer 1
  dual_gemm128<<<gg, 256, 0, stream>>>(bufC, Wl1, Wr1, b1, bufA, bufB, N);
  agg128_relu<<<nb, 256, 0, stream>>>(bufA, bufB, row_ptr, col, bufC, N);
  // layer 2 (40-dim) + log_softmax
  long long tg = (long long)((N + 3) / 4) * 80;
  int gb = (int)((tg + THREADS - 1) / THREADS);
  dual_gemm40<<<gb, 256, 0, stream>>>(bufC, Wl2, Wr2, b2, bufA, bufB, N);
  agg40_lsm<<<nb, 256, 0, stream>>>(bufA, bufB, row_ptr, col, (float*)d_out, N);
}

// Round 2
// 1110.404 us; speedup vs baseline: 1.5844x; 1.5844x over previous
//
#include <hip/hip_runtime.h>
#include <math.h>

#define THREADS 256

// ---------------- CSR build ----------------

__global__ void k_deg(const int* __restrict__ dst, int* __restrict__ deg, int E) {
  int e = blockIdx.x * blockDim.x + threadIdx.x;
  if (e < E) atomicAdd(&deg[dst[e]], 1);
}

// single-block chunked exclusive scan: deg[0..n) -> row_ptr[0..n]
__global__ void k_scan(const int* __restrict__ deg, int* __restrict__ row_ptr, int n) {
  __shared__ int sums[1024];
  int t = threadIdx.x;
  int chunk = (n + 1023) >> 10;
  int begin = t * chunk;
  int end = min(begin + chunk, n);
  int s = 0;
  for (int i = begin; i < end; ++i) s += deg[i];
  sums[t] = s;
  __syncthreads();
  for (int off = 1; off < 1024; off <<= 1) {
    int v = (t >= off) ? sums[t - off] : 0;
    __syncthreads();
    if (t >= off) sums[t] += v;
    __syncthreads();
  }
  int run = sums[t] - s;  // exclusive prefix of this chunk
  for (int i = begin; i < end; ++i) { row_ptr[i] = run; run += deg[i]; }
  if (end == n) row_ptr[n] = run;
}

__global__ void k_fill(const int* __restrict__ src, const int* __restrict__ dst,
                       const int* __restrict__ row_ptr, int* __restrict__ cursor,
                       int* __restrict__ col, int E) {
  int e = blockIdx.x * blockDim.x + threadIdx.x;
  if (e < E) {
    int d = dst[e];
    int p = atomicAdd(&cursor[d], 1);
    col[row_ptr[d] + p] = src[e];
  }
}

// ---------------- dual GEMM, D=128 ----------------
// outL = X@Wl ; outR = X@Wr + b   (X:[M,128], W:[128,128] row-major)
// blockIdx.y selects side. BM=64 rows/block, 256 threads, 4x8 register tile.
__global__ __launch_bounds__(256) void dual_gemm128(
    const float* __restrict__ X, const float* __restrict__ Wl,
    const float* __restrict__ Wr, const float* __restrict__ b,
    float* __restrict__ outL, float* __restrict__ outR, int M) {
  __shared__ float Xs[128 * 64];  // [k][r], 32KB (transposed X tile)
  __shared__ float Ws[32 * 128];  // [k][c] chunk, 16KB
  const float* W = blockIdx.y ? Wr : Wl;
  float* out = blockIdx.y ? outR : outL;
  int row0 = blockIdx.x * 64;
  int tid = threadIdx.x;

  // stage X tile transposed (one-time, conflicts amortized)
  {
    int rbase = tid >> 5;       // 0..7
    int kq = tid & 31;          // float4 index along k
    for (int rr = rbase; rr < 64; rr += 8) {
      int row = row0 + rr;
      float4 v = make_float4(0.f, 0.f, 0.f, 0.f);
      if (row < M) v = ((const float4*)(X + (size_t)row * 128))[kq];
      int k = kq * 4;
      Xs[(k + 0) * 64 + rr] = v.x;
      Xs[(k + 1) * 64 + rr] = v.y;
      Xs[(k + 2) * 64 + rr] = v.z;
      Xs[(k + 3) * 64 + rr] = v.w;
    }
  }

  float acc[4][8];
#pragma unroll
  for (int i = 0; i < 4; ++i)
#pragma unroll
    for (int j = 0; j < 8; ++j) acc[i][j] = 0.f;

  int tx = tid & 15, ty = tid >> 4;
  int r0 = ty * 4;
  int c0 = tx * 4;  // cols c0..c0+3 and c0+64..c0+67 (2-way LDS alias = free)

  for (int kk = 0; kk < 128; kk += 32) {
    __syncthreads();  // protects Xs (first iter) and Ws reuse
    for (int i = tid; i < 1024; i += 256) {  // 1024 float4s = 32x128 chunk
      int k = i >> 5, cq = i & 31;
      ((float4*)Ws)[i] = ((const float4*)(W + (size_t)(kk + k) * 128))[cq];
    }
    __syncthreads();
#pragma unroll
    for (int k = 0; k < 32; ++k) {
      const float4 xv = *(const float4*)&Xs[(kk + k) * 64 + r0];
      const float4 wa = *(const float4*)&Ws[k * 128 + c0];
      const float4 wb = *(const float4*)&Ws[k * 128 + c0 + 64];
      float xf[4] = {xv.x, xv.y, xv.z, xv.w};
      float wf[8] = {wa.x, wa.y, wa.z, wa.w, wb.x, wb.y, wb.z, wb.w};
#pragma unroll
      for (int i = 0; i < 4; ++i)
#pragma unroll
        for (int j = 0; j < 8; ++j) acc[i][j] = fmaf(xf[i], wf[j], acc[i][j]);
    }
  }

  float bl[8] = {0.f, 0.f, 0.f, 0.f, 0.f, 0.f, 0.f, 0.f};
  if (blockIdx.y) {
#pragma unroll
    for (int j = 0; j < 4; ++j) { bl[j] = b[c0 + j]; bl[4 + j] = b[c0 + 64 + j]; }
  }
#pragma unroll
  for (int i = 0; i < 4; ++i) {
    int row = row0 + r0 + i;
    if (row >= M) continue;
    float4 o0, o1;
    o0.x = acc[i][0] + bl[0]; o0.y = acc[i][1] + bl[1];
    o0.z = acc[i][2] + bl[2]; o0.w = acc[i][3] + bl[3];
    o1.x = acc[i][4] + bl[4]; o1.y = acc[i][5] + bl[5];
    o1.z = acc[i][6] + bl[6]; o1.w = acc[i][7] + bl[7];
    *(float4*)&out[(size_t)row * 128 + c0] = o0;
    *(float4*)&out[(size_t)row * 128 + c0 + 64] = o1;
  }
}

// ---------------- dual GEMM, D=40 (layer 2) — LDS-staged rewrite ----------------
// Round-1 version spilled: VGPR=256, WRITE_SIZE 1.12GB of scratch traffic, 761us.
// Cause: 4 row pointers x fully-unrolled 32x float4 global loads -> compiler
// hoisted ~128 long-latency loads, blew the register file. Fix: same shape as
// dual_gemm128 — X tile transposed in LDS (32KB), W staged in 32x80 k-chunks
// (10KB), inner loop touches only short-latency LDS. 42KB LDS -> 3 blocks/CU.
// Thread tile: 4 rows x 5 cols (c80<40 -> Wl/outL, else Wr/outR+bias).
__global__ __launch_bounds__(256) void dual_gemm40(
    const float* __restrict__ X, const float* __restrict__ Wl,
    const float* __restrict__ Wr, const float* __restrict__ b,
    float* __restrict__ outL, float* __restrict__ outR, int M) {
  __shared__ float Xs[128 * 64];  // [k][r] transposed, 32 KB
  __shared__ float Wsc[32 * 80];  // [k-chunk][c80], 10 KB
  int row0 = blockIdx.x * 64;
  int tid = threadIdx.x;

  // stage X tile transposed (identical pattern to dual_gemm128)
  {
    int rbase = tid >> 5;       // 0..7
    int kq = tid & 31;          // float4 index along k
    for (int rr = rbase; rr < 64; rr += 8) {
      int row = row0 + rr;
      float4 v = make_float4(0.f, 0.f, 0.f, 0.f);
      if (row < M) v = ((const float4*)(X + (size_t)row * 128))[kq];
      int k = kq * 4;
      Xs[(k + 0) * 64 + rr] = v.x;
      Xs[(k + 1) * 64 + rr] = v.y;
      Xs[(k + 2) * 64 + rr] = v.z;
      Xs[(k + 3) * 64 + rr] = v.w;
    }
  }

  float acc[4][5];
#pragma unroll
  for (int i = 0; i < 4; ++i)
#pragma unroll
    for (int j = 0; j < 5; ++j) acc[i][j] = 0.f;

  int tx = tid & 15, ty = tid >> 4;  // 16 col-groups x 16 row-groups
  int r0 = ty * 4;                   // rows r0..r0+3 (float4-aligned in Xs)
  int c0 = tx * 5;                   // cols c0..c0+4; gcd(5,32)=1 -> 16 distinct
                                     // banks per tx, same-tx = broadcast: no conflicts

  for (int kk = 0; kk < 128; kk += 32) {
    __syncthreads();  // protects Xs (first iter) and Wsc reuse
    for (int i = tid; i < 32 * 80; i += 256) {
      int k = i / 80, c = i - k * 80;
      Wsc[i] = (c < 40) ? Wl[(kk + k) * 40 + c] : Wr[(kk + k) * 40 + (c - 40)];
    }
    __syncthreads();
#pragma unroll 8
    for (int k = 0; k < 32; ++k) {
      const float4 xv = *(const float4*)&Xs[(kk + k) * 64 + r0];
      float xf[4] = {xv.x, xv.y, xv.z, xv.w};
      const float* wp = &Wsc[k * 80 + c0];
#pragma unroll
      for (int j = 0; j < 5; ++j) {
        float w = wp[j];
#pragma unroll
        for (int i = 0; i < 4; ++i) acc[i][j] = fmaf(xf[i], w, acc[i][j]);
      }
    }
  }

#pragma unroll
  for (int j = 0; j < 5; ++j) {
    int c80 = c0 + j;
    bool right = c80 >= 40;
    int c = right ? (c80 - 40) : c80;
    float bias = right ? b[c] : 0.f;
    float* out = right ? outR : outL;
#pragma unroll
    for (int i = 0; i < 4; ++i) {
      int row = row0 + r0 + i;
      if (row < M) out[(size_t)row * 40 + c] = acc[i][j] + bias;
    }
  }
}

// ---------------- aggregation D=128, fused deg_inv + add + relu ----------------
// h[n] = relu(deg_inv[n] * sum_{e in CSR(n)} xl[col[e]] + xr[n])
__global__ __launch_bounds__(256) void agg128_relu(
    const float* __restrict__ xl, const float* __restrict__ xr,
    const int* __restrict__ row_ptr, const int* __restrict__ col,
    float* __restrict__ h, int Nn) {
  int wave = threadIdx.x >> 6;
  int lane = threadIdx.x & 63;
  int n = blockIdx.x * 4 + wave;
  if (n >= Nn) return;
  int beg = row_ptr[n], end = row_ptr[n + 1];
  const float2* xl2 = (const float2*)xl;
  float ax = 0.f, ay = 0.f;
  int e = beg;
  for (; e + 2 <= end; e += 2) {
    int s0 = col[e], s1 = col[e + 1];
    float2 v0 = xl2[(size_t)s0 * 64 + lane];
    float2 v1 = xl2[(size_t)s1 * 64 + lane];
    ax += v0.x + v1.x;
    ay += v0.y + v1.y;
  }
  if (e < end) {
    int s0 = col[e];
    float2 v0 = xl2[(size_t)s0 * 64 + lane];
    ax += v0.x; ay += v0.y;
  }
  float di = 1.0f / (float)max(end - beg, 1);
  float2 rv = ((const float2*)xr)[(size_t)n * 64 + lane];
  float2 o;
  o.x = fmaxf(fmaf(ax, di, rv.x), 0.f);
  o.y = fmaxf(fmaf(ay, di, rv.y), 0.f);
  ((float2*)h)[(size_t)n * 64 + lane] = o;
}

// ---------------- aggregation D=40, fused deg_inv + add + log_softmax ----------------
__global__ __launch_bounds__(256) void agg40_lsm(
    const float* __restrict__ tl, const float* __restrict__ tr,
    const int* __restrict__ row_ptr, const int* __restrict__ col,
    float* __restrict__ out, int Nn) {
  int wave = threadIdx.x >> 6;
  int lane = threadIdx.x & 63;
  int n = blockIdx.x * 4 + wave;
  if (n >= Nn) return;
  int beg = row_ptr[n], end = row_ptr[n + 1];
  bool active = lane < 40;
  int li = active ? lane : 0;
  float acc = 0.f;
  int e = beg;
  for (; e + 2 <= end; e += 2) {
    int s0 = col[e], s1 = col[e + 1];
    acc += tl[(size_t)s0 * 40 + li] + tl[(size_t)s1 * 40 + li];
  }
  if (e < end) acc += tl[(size_t)col[e] * 40 + li];
  float di = 1.0f / (float)max(end - beg, 1);
  float v = active ? fmaf(acc, di, tr[(size_t)n * 40 + lane]) : -INFINITY;
  float m = v;
#pragma unroll
  for (int off = 32; off; off >>= 1) m = fmaxf(m, __shfl_xor(m, off));
  float ex = active ? expf(v - m) : 0.f;
  float ssum = ex;
#pragma unroll
  for (int off = 32; off; off >>= 1) ssum += __shfl_xor(ssum, off);
  if (active) out[(size_t)n * 40 + lane] = (v - m) - logf(ssum);
}

// ---------------- launcher ----------------

extern "C" void kernel_launch(void* const* d_in, const int* in_sizes, int n_in,
                              void* d_out, int out_size, void* d_ws, size_t ws_size,
                              hipStream_t stream) {
  const float* x   = (const float*)d_in[0];
  const int*   ei  = (const int*)d_in[1];
  const float* Wl0 = (const float*)d_in[2];
  const float* Wr0 = (const float*)d_in[3];
  const float* b0  = (const float*)d_in[4];
  const float* Wl1 = (const float*)d_in[5];
  const float* Wr1 = (const float*)d_in[6];
  const float* b1  = (const float*)d_in[7];
  const float* Wl2 = (const float*)d_in[8];
  const float* Wr2 = (const float*)d_in[9];
  const float* b2  = (const float*)d_in[10];

  int N = in_sizes[0] / 128;
  int E = in_sizes[1] / 2;
  const int* src = ei;
  const int* dst = ei + E;

  char* ws = (char*)d_ws;
  size_t off = 0;
  auto alloc = [&](size_t bytes) -> void* {
    void* p = ws + off;
    off += (bytes + 255) & ~(size_t)255;
    return p;
  };
  float* bufA   = (float*)alloc((size_t)N * 128 * 4);
  float* bufB   = (float*)alloc((size_t)N * 128 * 4);
  float* bufC   = (float*)alloc((size_t)N * 128 * 4);
  int* row_ptr  = (int*)alloc((size_t)(N + 1) * 4);
  int* deg      = (int*)alloc((size_t)N * 4);
  int* cursor   = (int*)alloc((size_t)N * 4);
  int* col      = (int*)alloc((size_t)E * 4);
  (void)ws_size; (void)n_in; (void)out_size;

  hipMemsetAsync(deg, 0, (size_t)N * 4, stream);
  hipMemsetAsync(cursor, 0, (size_t)N * 4, stream);

  int eb = (E + THREADS - 1) / THREADS;
  k_deg<<<eb, THREADS, 0, stream>>>(dst, deg, E);
  k_scan<<<1, 1024, 0, stream>>>(deg, row_ptr, N);
  k_fill<<<eb, THREADS, 0, stream>>>(src, dst, row_ptr, cursor, col, E);

  dim3 gg((N + 63) / 64, 2);
  int nb = (N + 3) / 4;

  // layer 0
  dual_gemm128<<<gg, 256, 0, stream>>>(x, Wl0, Wr0, b0, bufA, bufB, N);
  agg128_relu<<<nb, 256, 0, stream>>>(bufA, bufB, row_ptr, col, bufC, N);
  // layer 1
  dual_gemm128<<<gg, 256, 0, stream>>>(bufC, Wl1, Wr1, b1, bufA, bufB, N);
  agg128_relu<<<nb, 256, 0, stream>>>(bufA, bufB, row_ptr, col, bufC, N);
  // layer 2 (40-dim) + log_softmax
  dual_gemm40<<<(N + 63) / 64, 256, 0, stream>>>(bufC, Wl2, Wr2, b2, bufA, bufB, N);
  agg40_lsm<<<nb, 256, 0, stream>>>(bufA, bufB, row_ptr, col, (float*)d_out, N);
}

// Round 3
// 941.734 us; speedup vs baseline: 1.8681x; 1.1791x over previous
//
#include <hip/hip_runtime.h>
#include <math.h>

#define THREADS 256

// ---------------- CSR build ----------------

__global__ void k_deg(const int* __restrict__ dst, int* __restrict__ deg, int E) {
  int e = blockIdx.x * blockDim.x + threadIdx.x;
  if (e < E) atomicAdd(&deg[dst[e]], 1);
}

// Parallel 3-phase exclusive scan. Round-2's single-block k_scan was the
// slowest dispatch on the chip (162us, 0.16% occupancy, stride-392B loads).
// Phase 1: per-block (1024 elems) sums, coalesced int4.
__global__ __launch_bounds__(256) void k_scan_blocks(const int* __restrict__ deg,
                                                     int* __restrict__ bsum, int n) {
  int b = blockIdx.x, t = threadIdx.x;
  int base = b * 1024 + t * 4;
  int s = 0;
  if (base + 3 < n) {
    int4 v = *(const int4*)(deg + base);
    s = v.x + v.y + v.z + v.w;
  } else {
#pragma unroll
    for (int j = 0; j < 4; ++j) if (base + j < n) s += deg[base + j];
  }
#pragma unroll
  for (int off = 32; off; off >>= 1) s += __shfl_xor(s, off);
  __shared__ int red[4];
  if ((t & 63) == 0) red[t >> 6] = s;
  __syncthreads();
  if (t == 0) bsum[b] = red[0] + red[1] + red[2] + red[3];
}

// Phase 2: single-block exclusive scan of the (<=256) block sums; also writes
// row_ptr[n] = E (the known total).
__global__ __launch_bounds__(256) void k_scan_top(const int* __restrict__ bsum,
                                                  int* __restrict__ boffs, int nb,
                                                  int* __restrict__ row_ptr, int n, int E) {
  __shared__ int sh[256];
  int t = threadIdx.x;
  int v = (t < nb) ? bsum[t] : 0;
  sh[t] = v;
  __syncthreads();
  for (int off = 1; off < 256; off <<= 1) {
    int u = (t >= off) ? sh[t - off] : 0;
    __syncthreads();
    if (t >= off) sh[t] += u;
    __syncthreads();
  }
  if (t < nb) boffs[t] = sh[t] - v;  // exclusive
  if (t == 0) row_ptr[n] = E;
}

// Phase 3: re-read deg, intra-block exclusive scan, add block offset, write row_ptr.
__global__ __launch_bounds__(256) void k_scan_write(const int* __restrict__ deg,
                                                    const int* __restrict__ boffs,
                                                    int* __restrict__ row_ptr, int n) {
  int b = blockIdx.x, t = threadIdx.x;
  int base = b * 1024 + t * 4;
  int v0 = 0, v1 = 0, v2 = 0, v3 = 0;
  if (base + 3 < n) {
    int4 q = *(const int4*)(deg + base);
    v0 = q.x; v1 = q.y; v2 = q.z; v3 = q.w;
  } else {
    if (base + 0 < n) v0 = deg[base + 0];
    if (base + 1 < n) v1 = deg[base + 1];
    if (base + 2 < n) v2 = deg[base + 2];
    if (base + 3 < n) v3 = deg[base + 3];
  }
  int s = v0 + v1 + v2 + v3;
  __shared__ int sh[256];
  sh[t] = s;
  __syncthreads();
  for (int off = 1; off < 256; off <<= 1) {
    int u = (t >= off) ? sh[t - off] : 0;
    __syncthreads();
    if (t >= off) sh[t] += u;
    __syncthreads();
  }
  int pre = boffs[b] + sh[t] - s;
  int o0 = pre, o1 = pre + v0, o2 = o1 + v1, o3 = o2 + v2;
  if (base + 3 < n) {
    *(int4*)(row_ptr + base) = make_int4(o0, o1, o2, o3);
  } else {
    if (base + 0 < n) row_ptr[base + 0] = o0;
    if (base + 1 < n) row_ptr[base + 1] = o1;
    if (base + 2 < n) row_ptr[base + 2] = o2;
    if (base + 3 < n) row_ptr[base + 3] = o3;
  }
}

__global__ void k_fill(const int* __restrict__ src, const int* __restrict__ dst,
                       const int* __restrict__ row_ptr, int* __restrict__ cursor,
                       int* __restrict__ col, int E) {
  int e = blockIdx.x * blockDim.x + threadIdx.x;
  if (e < E) {
    int d = dst[e];
    int p = atomicAdd(&cursor[d], 1);
    col[row_ptr[d] + p] = src[e];
  }
}

// ---------------- dual GEMM, D=128 ----------------
// outL = X@Wl ; outR = X@Wr + b   (X:[M,128], W:[128,128] row-major)
// blockIdx.y selects side. BM=64 rows/block, 256 threads, 4x8 register tile.
__global__ __launch_bounds__(256) void dual_gemm128(
    const float* __restrict__ X, const float* __restrict__ Wl,
    const float* __restrict__ Wr, const float* __restrict__ b,
    float* __restrict__ outL, float* __restrict__ outR, int M) {
  __shared__ float Xs[128 * 64];  // [k][r], 32KB (transposed X tile)
  __shared__ float Ws[32 * 128];  // [k][c] chunk, 16KB
  const float* W = blockIdx.y ? Wr : Wl;
  float* out = blockIdx.y ? outR : outL;
  int row0 = blockIdx.x * 64;
  int tid = threadIdx.x;

  {
    int rbase = tid >> 5;
    int kq = tid & 31;
    for (int rr = rbase; rr < 64; rr += 8) {
      int row = row0 + rr;
      float4 v = make_float4(0.f, 0.f, 0.f, 0.f);
      if (row < M) v = ((const float4*)(X + (size_t)row * 128))[kq];
      int k = kq * 4;
      Xs[(k + 0) * 64 + rr] = v.x;
      Xs[(k + 1) * 64 + rr] = v.y;
      Xs[(k + 2) * 64 + rr] = v.z;
      Xs[(k + 3) * 64 + rr] = v.w;
    }
  }

  float acc[4][8];
#pragma unroll
  for (int i = 0; i < 4; ++i)
#pragma unroll
    for (int j = 0; j < 8; ++j) acc[i][j] = 0.f;

  int tx = tid & 15, ty = tid >> 4;
  int r0 = ty * 4;
  int c0 = tx * 4;

  for (int kk = 0; kk < 128; kk += 32) {
    __syncthreads();
    for (int i = tid; i < 1024; i += 256) {
      int k = i >> 5, cq = i & 31;
      ((float4*)Ws)[i] = ((const float4*)(W + (size_t)(kk + k) * 128))[cq];
    }
    __syncthreads();
#pragma unroll
    for (int k = 0; k < 32; ++k) {
      const float4 xv = *(const float4*)&Xs[(kk + k) * 64 + r0];
      const float4 wa = *(const float4*)&Ws[k * 128 + c0];
      const float4 wb = *(const float4*)&Ws[k * 128 + c0 + 64];
      float xf[4] = {xv.x, xv.y, xv.z, xv.w};
      float wf[8] = {wa.x, wa.y, wa.z, wa.w, wb.x, wb.y, wb.z, wb.w};
#pragma unroll
      for (int i = 0; i < 4; ++i)
#pragma unroll
        for (int j = 0; j < 8; ++j) acc[i][j] = fmaf(xf[i], wf[j], acc[i][j]);
    }
  }

  float bl[8] = {0.f, 0.f, 0.f, 0.f, 0.f, 0.f, 0.f, 0.f};
  if (blockIdx.y) {
#pragma unroll
    for (int j = 0; j < 4; ++j) { bl[j] = b[c0 + j]; bl[4 + j] = b[c0 + 64 + j]; }
  }
#pragma unroll
  for (int i = 0; i < 4; ++i) {
    int row = row0 + r0 + i;
    if (row >= M) continue;
    float4 o0, o1;
    o0.x = acc[i][0] + bl[0]; o0.y = acc[i][1] + bl[1];
    o0.z = acc[i][2] + bl[2]; o0.w = acc[i][3] + bl[3];
    o1.x = acc[i][4] + bl[4]; o1.y = acc[i][5] + bl[5];
    o1.z = acc[i][6] + bl[6]; o1.w = acc[i][7] + bl[7];
    *(float4*)&out[(size_t)row * 128 + c0] = o0;
    *(float4*)&out[(size_t)row * 128 + c0 + 64] = o1;
  }
}

// ---------------- dual GEMM, D=40 (layer 2) — LDS-staged ----------------
__global__ __launch_bounds__(256) void dual_gemm40(
    const float* __restrict__ X, const float* __restrict__ Wl,
    const float* __restrict__ Wr, const float* __restrict__ b,
    float* __restrict__ outL, float* __restrict__ outR, int M) {
  __shared__ float Xs[128 * 64];
  __shared__ float Wsc[32 * 80];
  int row0 = blockIdx.x * 64;
  int tid = threadIdx.x;

  {
    int rbase = tid >> 5;
    int kq = tid & 31;
    for (int rr = rbase; rr < 64; rr += 8) {
      int row = row0 + rr;
      float4 v = make_float4(0.f, 0.f, 0.f, 0.f);
      if (row < M) v = ((const float4*)(X + (size_t)row * 128))[kq];
      int k = kq * 4;
      Xs[(k + 0) * 64 + rr] = v.x;
      Xs[(k + 1) * 64 + rr] = v.y;
      Xs[(k + 2) * 64 + rr] = v.z;
      Xs[(k + 3) * 64 + rr] = v.w;
    }
  }

  float acc[4][5];
#pragma unroll
  for (int i = 0; i < 4; ++i)
#pragma unroll
    for (int j = 0; j < 5; ++j) acc[i][j] = 0.f;

  int tx = tid & 15, ty = tid >> 4;
  int r0 = ty * 4;
  int c0 = tx * 5;

  for (int kk = 0; kk < 128; kk += 32) {
    __syncthreads();
    for (int i = tid; i < 32 * 80; i += 256) {
      int k = i / 80, c = i - k * 80;
      Wsc[i] = (c < 40) ? Wl[(kk + k) * 40 + c] : Wr[(kk + k) * 40 + (c - 40)];
    }
    __syncthreads();
#pragma unroll 8
    for (int k = 0; k < 32; ++k) {
      const float4 xv = *(const float4*)&Xs[(kk + k) * 64 + r0];
      float xf[4] = {xv.x, xv.y, xv.z, xv.w};
      const float* wp = &Wsc[k * 80 + c0];
#pragma unroll
      for (int j = 0; j < 5; ++j) {
        float w = wp[j];
#pragma unroll
        for (int i = 0; i < 4; ++i) acc[i][j] = fmaf(xf[i], w, acc[i][j]);
      }
    }
  }

#pragma unroll
  for (int j = 0; j < 5; ++j) {
    int c80 = c0 + j;
    bool right = c80 >= 40;
    int c = right ? (c80 - 40) : c80;
    float bias = right ? b[c] : 0.f;
    float* out = right ? outR : outL;
#pragma unroll
    for (int i = 0; i < 4; ++i) {
      int row = row0 + r0 + i;
      if (row < M) out[(size_t)row * 40 + c] = acc[i][j] + bias;
    }
  }
}

// ---------------- aggregation D=128, fused deg_inv + add + relu ----------------
// h[n] = relu(deg_inv[n]*sum_{e in CSR(n)} xl[col[e]] + xr[n])
// Round-3: float4/lane, half-wave per edge — each iteration gathers 4 rows
// (2x float4 loads x 2 rows each) vs round-2's 2 rows; halves trip count,
// doubles outstanding bytes. Halves combined via shfl_xor(32) at the end.
__global__ __launch_bounds__(256) void agg128_relu(
    const float* __restrict__ xl, const float* __restrict__ xr,
    const int* __restrict__ row_ptr, const int* __restrict__ col,
    float* __restrict__ h, int Nn) {
  int wave = threadIdx.x >> 6;
  int lane = threadIdx.x & 63;
  int half = lane >> 5;   // which edge of the pair this half-wave gathers
  int l32 = lane & 31;    // float4 index within the 128-float row
  int n = blockIdx.x * 4 + wave;
  if (n >= Nn) return;
  int beg = row_ptr[n], end = row_ptr[n + 1];
  const float4* xl4 = (const float4*)xl;
  float4 a0 = make_float4(0.f, 0.f, 0.f, 0.f);
  float4 a1 = make_float4(0.f, 0.f, 0.f, 0.f);
  int e = beg + half;           // this half-wave owns edges beg+half, +2, +4, ...
  for (; e + 2 < end; e += 4) { // unroll 2: edges e and e+2 per iteration
    int s0 = col[e], s1 = col[e + 2];
    float4 v0 = xl4[(size_t)s0 * 32 + l32];
    float4 v1 = xl4[(size_t)s1 * 32 + l32];
    a0.x += v0.x; a0.y += v0.y; a0.z += v0.z; a0.w += v0.w;
    a1.x += v1.x; a1.y += v1.y; a1.z += v1.z; a1.w += v1.w;
  }
  if (e < end) {
    int s0 = col[e];
    float4 v0 = xl4[(size_t)s0 * 32 + l32];
    a0.x += v0.x; a0.y += v0.y; a0.z += v0.z; a0.w += v0.w;
  }
  a0.x += a1.x; a0.y += a1.y; a0.z += a1.z; a0.w += a1.w;
  // combine the two half-wave partials (lane <-> lane^32)
  a0.x += __shfl_xor(a0.x, 32);
  a0.y += __shfl_xor(a0.y, 32);
  a0.z += __shfl_xor(a0.z, 32);
  a0.w += __shfl_xor(a0.w, 32);
  if (half == 0) {
    float di = 1.0f / (float)max(end - beg, 1);
    float4 rv = ((const float4*)xr)[(size_t)n * 32 + l32];
    float4 o;
    o.x = fmaxf(fmaf(a0.x, di, rv.x), 0.f);
    o.y = fmaxf(fmaf(a0.y, di, rv.y), 0.f);
    o.z = fmaxf(fmaf(a0.z, di, rv.z), 0.f);
    o.w = fmaxf(fmaf(a0.w, di, rv.w), 0.f);
    ((float4*)h)[(size_t)n * 32 + l32] = o;
  }
}

// ---------------- aggregation D=40, fused deg_inv + add + log_softmax ----------------
__global__ __launch_bounds__(256) void agg40_lsm(
    const float* __restrict__ tl, const float* __restrict__ tr,
    const int* __restrict__ row_ptr, const int* __restrict__ col,
    float* __restrict__ out, int Nn) {
  int wave = threadIdx.x >> 6;
  int lane = threadIdx.x & 63;
  int n = blockIdx.x * 4 + wave;
  if (n >= Nn) return;
  int beg = row_ptr[n], end = row_ptr[n + 1];
  bool active = lane < 40;
  int li = active ? lane : 0;
  float acc = 0.f;
  int e = beg;
  for (; e + 2 <= end; e += 2) {
    int s0 = col[e], s1 = col[e + 1];
    acc += tl[(size_t)s0 * 40 + li] + tl[(size_t)s1 * 40 + li];
  }
  if (e < end) acc += tl[(size_t)col[e] * 40 + li];
  float di = 1.0f / (float)max(end - beg, 1);
  float v = active ? fmaf(acc, di, tr[(size_t)n * 40 + lane]) : -INFINITY;
  float m = v;
#pragma unroll
  for (int off = 32; off; off >>= 1) m = fmaxf(m, __shfl_xor(m, off));
  float ex = active ? expf(v - m) : 0.f;
  float ssum = ex;
#pragma unroll
  for (int off = 32; off; off >>= 1) ssum += __shfl_xor(ssum, off);
  if (active) out[(size_t)n * 40 + lane] = (v - m) - logf(ssum);
}

// ---------------- launcher ----------------

extern "C" void kernel_launch(void* const* d_in, const int* in_sizes, int n_in,
                              void* d_out, int out_size, void* d_ws, size_t ws_size,
                              hipStream_t stream) {
  const float* x   = (const float*)d_in[0];
  const int*   ei  = (const int*)d_in[1];
  const float* Wl0 = (const float*)d_in[2];
  const float* Wr0 = (const float*)d_in[3];
  const float* b0  = (const float*)d_in[4];
  const float* Wl1 = (const float*)d_in[5];
  const float* Wr1 = (const float*)d_in[6];
  const float* b1  = (const float*)d_in[7];
  const float* Wl2 = (const float*)d_in[8];
  const float* Wr2 = (const float*)d_in[9];
  const float* b2  = (const float*)d_in[10];

  int N = in_sizes[0] / 128;
  int E = in_sizes[1] / 2;
  const int* src = ei;
  const int* dst = ei + E;

  char* ws = (char*)d_ws;
  size_t off = 0;
  auto alloc = [&](size_t bytes) -> void* {
    void* p = ws + off;
    off += (bytes + 255) & ~(size_t)255;
    return p;
  };
  float* bufA   = (float*)alloc((size_t)N * 128 * 4);
  float* bufB   = (float*)alloc((size_t)N * 128 * 4);
  float* bufC   = (float*)alloc((size_t)N * 128 * 4);
  int* row_ptr  = (int*)alloc((size_t)(N + 1) * 4);
  int* deg      = (int*)alloc((size_t)N * 4);
  int* cursor   = (int*)alloc((size_t)N * 4);
  int* col      = (int*)alloc((size_t)E * 4);
  int* bsum     = (int*)alloc(256 * 4);
  int* boffs    = (int*)alloc(256 * 4);
  (void)ws_size; (void)n_in; (void)out_size;

  hipMemsetAsync(deg, 0, (size_t)N * 4, stream);
  hipMemsetAsync(cursor, 0, (size_t)N * 4, stream);

  int eb = (E + THREADS - 1) / THREADS;
  int nbscan = (N + 1023) / 1024;  // 98 blocks; k_scan_top supports up to 256
  k_deg<<<eb, THREADS, 0, stream>>>(dst, deg, E);
  k_scan_blocks<<<nbscan, 256, 0, stream>>>(deg, bsum, N);
  k_scan_top<<<1, 256, 0, stream>>>(bsum, boffs, nbscan, row_ptr, N, E);
  k_scan_write<<<nbscan, 256, 0, stream>>>(deg, boffs, row_ptr, N);
  k_fill<<<eb, THREADS, 0, stream>>>(src, dst, row_ptr, cursor, col, E);

  dim3 gg((N + 63) / 64, 2);
  int nb = (N + 3) / 4;

  // layer 0
  dual_gemm128<<<gg, 256, 0, stream>>>(x, Wl0, Wr0, b0, bufA, bufB, N);
  agg128_relu<<<nb, 256, 0, stream>>>(bufA, bufB, row_ptr, col, bufC, N);
  // layer 1
  dual_gemm128<<<gg, 256, 0, stream>>>(bufC, Wl1, Wr1, b1, bufA, bufB, N);
  agg128_relu<<<nb, 256, 0, stream>>>(bufA, bufB, row_ptr, col, bufC, N);
  // layer 2 (40-dim) + log_softmax
  dual_gemm40<<<(N + 63) / 64, 256, 0, stream>>>(bufC, Wl2, Wr2, b2, bufA, bufB, N);
  agg40_lsm<<<nb, 256, 0, stream>>>(bufA, bufB, row_ptr, col, (float*)d_out, N);
}

// Round 4
// 894.424 us; speedup vs baseline: 1.9669x; 1.0529x over previous
//
#include <hip/hip_runtime.h>
#include <math.h>

#define THREADS 256

// ---------------- CSR build ----------------

__global__ void k_deg(const int* __restrict__ dst, int* __restrict__ deg, int E) {
  int e = blockIdx.x * blockDim.x + threadIdx.x;
  if (e < E) atomicAdd(&deg[dst[e]], 1);
}

// Parallel 3-phase exclusive scan (round-3; single-block scan was 162us).
__global__ __launch_bounds__(256) void k_scan_blocks(const int* __restrict__ deg,
                                                     int* __restrict__ bsum, int n) {
  int b = blockIdx.x, t = threadIdx.x;
  int base = b * 1024 + t * 4;
  int s = 0;
  if (base + 3 < n) {
    int4 v = *(const int4*)(deg + base);
    s = v.x + v.y + v.z + v.w;
  } else {
#pragma unroll
    for (int j = 0; j < 4; ++j) if (base + j < n) s += deg[base + j];
  }
#pragma unroll
  for (int off = 32; off; off >>= 1) s += __shfl_xor(s, off);
  __shared__ int red[4];
  if ((t & 63) == 0) red[t >> 6] = s;
  __syncthreads();
  if (t == 0) bsum[b] = red[0] + red[1] + red[2] + red[3];
}

__global__ __launch_bounds__(256) void k_scan_top(const int* __restrict__ bsum,
                                                  int* __restrict__ boffs, int nb,
                                                  int* __restrict__ row_ptr, int n, int E) {
  __shared__ int sh[256];
  int t = threadIdx.x;
  int v = (t < nb) ? bsum[t] : 0;
  sh[t] = v;
  __syncthreads();
  for (int off = 1; off < 256; off <<= 1) {
    int u = (t >= off) ? sh[t - off] : 0;
    __syncthreads();
    if (t >= off) sh[t] += u;
    __syncthreads();
  }
  if (t < nb) boffs[t] = sh[t] - v;  // exclusive
  if (t == 0) row_ptr[n] = E;
}

__global__ __launch_bounds__(256) void k_scan_write(const int* __restrict__ deg,
                                                    const int* __restrict__ boffs,
                                                    int* __restrict__ row_ptr, int n) {
  int b = blockIdx.x, t = threadIdx.x;
  int base = b * 1024 + t * 4;
  int v0 = 0, v1 = 0, v2 = 0, v3 = 0;
  if (base + 3 < n) {
    int4 q = *(const int4*)(deg + base);
    v0 = q.x; v1 = q.y; v2 = q.z; v3 = q.w;
  } else {
    if (base + 0 < n) v0 = deg[base + 0];
    if (base + 1 < n) v1 = deg[base + 1];
    if (base + 2 < n) v2 = deg[base + 2];
    if (base + 3 < n) v3 = deg[base + 3];
  }
  int s = v0 + v1 + v2 + v3;
  __shared__ int sh[256];
  sh[t] = s;
  __syncthreads();
  for (int off = 1; off < 256; off <<= 1) {
    int u = (t >= off) ? sh[t - off] : 0;
    __syncthreads();
    if (t >= off) sh[t] += u;
    __syncthreads();
  }
  int pre = boffs[b] + sh[t] - s;
  int o0 = pre, o1 = pre + v0, o2 = o1 + v1, o3 = o2 + v2;
  if (base + 3 < n) {
    *(int4*)(row_ptr + base) = make_int4(o0, o1, o2, o3);
  } else {
    if (base + 0 < n) row_ptr[base + 0] = o0;
    if (base + 1 < n) row_ptr[base + 1] = o1;
    if (base + 2 < n) row_ptr[base + 2] = o2;
    if (base + 3 < n) row_ptr[base + 3] = o3;
  }
}

__global__ void k_fill(const int* __restrict__ src, const int* __restrict__ dst,
                       const int* __restrict__ row_ptr, int* __restrict__ cursor,
                       int* __restrict__ col, int E) {
  int e = blockIdx.x * blockDim.x + threadIdx.x;
  if (e < E) {
    int d = dst[e];
    int p = atomicAdd(&cursor[d], 1);
    col[row_ptr[d] + p] = src[e];
  }
}

// ---------------- dual GEMM, D=128 — round-4 rewrite ----------------
// Round-3 counters: 150us/dispatch, SQ_LDS_BANK_CONFLICT=2.48e7 (~27% of CU
// cycles), VALUBusy 35%, VALU floor is 42us. Two fixes:
// (a) Conflict-free Xs staging: lane=row mapping -> writes Xs[k*64+rr] span
//     all 64 rr -> 32 banks x 2 lanes = free. (Old mapping: 32 lanes hit
//     one bank = 32-way write conflict.)
// (b) Both sides (Wl,Wr) merged in one block: Xs staged once, Ws holds
//     16x256 chunk (L cols 0..127, R cols 128..255), thread tile 4x16.
//     LDS = 32KB + 16KB = 48KB -> 3 blocks/CU.
__global__ __launch_bounds__(256) void dual_gemm128(
    const float* __restrict__ X, const float* __restrict__ Wl,
    const float* __restrict__ Wr, const float* __restrict__ b,
    float* __restrict__ outL, float* __restrict__ outR, int M) {
  __shared__ float Xs[128 * 64];  // [k][r] transposed, 32KB
  __shared__ float Ws[16 * 256];  // [k-chunk][c256], 16KB
  int row0 = blockIdx.x * 64;
  int tid = threadIdx.x;

  // conflict-free transposed staging: lane = row
  {
    int rr = tid & 63;
    int kq0 = tid >> 6;  // 0..3
    int row = row0 + rr;
    const float4* xrow = (const float4*)(X + (size_t)row * 128);
    bool ok = row < M;
#pragma unroll
    for (int kq = 0; kq < 32; kq += 4) {
      int kqi = kq + kq0;
      float4 v = ok ? xrow[kqi] : make_float4(0.f, 0.f, 0.f, 0.f);
      int k = kqi * 4;
      Xs[(k + 0) * 64 + rr] = v.x;
      Xs[(k + 1) * 64 + rr] = v.y;
      Xs[(k + 2) * 64 + rr] = v.z;
      Xs[(k + 3) * 64 + rr] = v.w;
    }
  }

  float acc[4][16];
#pragma unroll
  for (int i = 0; i < 4; ++i)
#pragma unroll
    for (int j = 0; j < 16; ++j) acc[i][j] = 0.f;

  int tx = tid & 15, ty = tid >> 4;
  int r0 = ty * 4;   // rows r0..r0+3 (float4-aligned in Xs)
  int c0 = tx * 4;   // cols c0+{0..3} at offsets 0,64,128,192 in Ws row

  const float4* Wl4 = (const float4*)Wl;
  const float4* Wr4 = (const float4*)Wr;

  for (int kk = 0; kk < 128; kk += 16) {
    __syncthreads();  // protects Xs (first iter) and Ws reuse
    // stage 16x256 chunk: 1024 float4s, 4 per thread; coalesced global,
    // contiguous LDS writes (conflict-free b128)
#pragma unroll
    for (int i = tid; i < 1024; i += 256) {
      int k = i >> 6, cq = i & 63;  // cq = float4 col index 0..63
      float4 v = (cq < 32) ? Wl4[(size_t)(kk + k) * 32 + cq]
                           : Wr4[(size_t)(kk + k) * 32 + (cq - 32)];
      ((float4*)Ws)[i] = v;
    }
    __syncthreads();
#pragma unroll
    for (int k = 0; k < 16; ++k) {
      const float4 xv = *(const float4*)&Xs[(kk + k) * 64 + r0];
      const float4 wa = *(const float4*)&Ws[k * 256 + c0];         // L c0
      const float4 wb = *(const float4*)&Ws[k * 256 + c0 + 64];    // L c0+64
      const float4 wc = *(const float4*)&Ws[k * 256 + c0 + 128];   // R c0
      const float4 wd = *(const float4*)&Ws[k * 256 + c0 + 192];   // R c0+64
      float xf[4] = {xv.x, xv.y, xv.z, xv.w};
      float wf[16] = {wa.x, wa.y, wa.z, wa.w, wb.x, wb.y, wb.z, wb.w,
                      wc.x, wc.y, wc.z, wc.w, wd.x, wd.y, wd.z, wd.w};
#pragma unroll
      for (int i = 0; i < 4; ++i)
#pragma unroll
        for (int j = 0; j < 16; ++j) acc[i][j] = fmaf(xf[i], wf[j], acc[i][j]);
    }
  }

  float bl[8];
#pragma unroll
  for (int j = 0; j < 4; ++j) { bl[j] = b[c0 + j]; bl[4 + j] = b[c0 + 64 + j]; }
#pragma unroll
  for (int i = 0; i < 4; ++i) {
    int row = row0 + r0 + i;
    if (row >= M) continue;
    float4 l0, l1, rv0, rv1;
    l0.x = acc[i][0]; l0.y = acc[i][1]; l0.z = acc[i][2]; l0.w = acc[i][3];
    l1.x = acc[i][4]; l1.y = acc[i][5]; l1.z = acc[i][6]; l1.w = acc[i][7];
    rv0.x = acc[i][8] + bl[0];  rv0.y = acc[i][9] + bl[1];
    rv0.z = acc[i][10] + bl[2]; rv0.w = acc[i][11] + bl[3];
    rv1.x = acc[i][12] + bl[4]; rv1.y = acc[i][13] + bl[5];
    rv1.z = acc[i][14] + bl[6]; rv1.w = acc[i][15] + bl[7];
    *(float4*)&outL[(size_t)row * 128 + c0] = l0;
    *(float4*)&outL[(size_t)row * 128 + c0 + 64] = l1;
    *(float4*)&outR[(size_t)row * 128 + c0] = rv0;
    *(float4*)&outR[(size_t)row * 128 + c0 + 64] = rv1;
  }
}

// ---------------- dual GEMM, D=40 (layer 2) — LDS-staged ----------------
// Round-4: same conflict-free lane=row Xs staging as dual_gemm128.
__global__ __launch_bounds__(256) void dual_gemm40(
    const float* __restrict__ X, const float* __restrict__ Wl,
    const float* __restrict__ Wr, const float* __restrict__ b,
    float* __restrict__ outL, float* __restrict__ outR, int M) {
  __shared__ float Xs[128 * 64];
  __shared__ float Wsc[32 * 80];
  int row0 = blockIdx.x * 64;
  int tid = threadIdx.x;

  {
    int rr = tid & 63;
    int kq0 = tid >> 6;
    int row = row0 + rr;
    const float4* xrow = (const float4*)(X + (size_t)row * 128);
    bool ok = row < M;
#pragma unroll
    for (int kq = 0; kq < 32; kq += 4) {
      int kqi = kq + kq0;
      float4 v = ok ? xrow[kqi] : make_float4(0.f, 0.f, 0.f, 0.f);
      int k = kqi * 4;
      Xs[(k + 0) * 64 + rr] = v.x;
      Xs[(k + 1) * 64 + rr] = v.y;
      Xs[(k + 2) * 64 + rr] = v.z;
      Xs[(k + 3) * 64 + rr] = v.w;
    }
  }

  float acc[4][5];
#pragma unroll
  for (int i = 0; i < 4; ++i)
#pragma unroll
    for (int j = 0; j < 5; ++j) acc[i][j] = 0.f;

  int tx = tid & 15, ty = tid >> 4;
  int r0 = ty * 4;
  int c0 = tx * 5;

  for (int kk = 0; kk < 128; kk += 32) {
    __syncthreads();
    for (int i = tid; i < 32 * 80; i += 256) {
      int k = i / 80, c = i - k * 80;
      Wsc[i] = (c < 40) ? Wl[(kk + k) * 40 + c] : Wr[(kk + k) * 40 + (c - 40)];
    }
    __syncthreads();
#pragma unroll 8
    for (int k = 0; k < 32; ++k) {
      const float4 xv = *(const float4*)&Xs[(kk + k) * 64 + r0];
      float xf[4] = {xv.x, xv.y, xv.z, xv.w};
      const float* wp = &Wsc[k * 80 + c0];
#pragma unroll
      for (int j = 0; j < 5; ++j) {
        float w = wp[j];
#pragma unroll
        for (int i = 0; i < 4; ++i) acc[i][j] = fmaf(xf[i], w, acc[i][j]);
      }
    }
  }

#pragma unroll
  for (int j = 0; j < 5; ++j) {
    int c80 = c0 + j;
    bool right = c80 >= 40;
    int c = right ? (c80 - 40) : c80;
    float bias = right ? b[c] : 0.f;
    float* out = right ? outR : outL;
#pragma unroll
    for (int i = 0; i < 4; ++i) {
      int row = row0 + r0 + i;
      if (row < M) out[(size_t)row * 40 + c] = acc[i][j] + bias;
    }
  }
}

// ---------------- aggregation D=128, fused deg_inv + add + relu ----------------
__global__ __launch_bounds__(256) void agg128_relu(
    const float* __restrict__ xl, const float* __restrict__ xr,
    const int* __restrict__ row_ptr, const int* __restrict__ col,
    float* __restrict__ h, int Nn) {
  int wave = threadIdx.x >> 6;
  int lane = threadIdx.x & 63;
  int half = lane >> 5;
  int l32 = lane & 31;
  int n = blockIdx.x * 4 + wave;
  if (n >= Nn) return;
  int beg = row_ptr[n], end = row_ptr[n + 1];
  const float4* xl4 = (const float4*)xl;
  float4 a0 = make_float4(0.f, 0.f, 0.f, 0.f);
  float4 a1 = make_float4(0.f, 0.f, 0.f, 0.f);
  int e = beg + half;
  for (; e + 2 < end; e += 4) {
    int s0 = col[e], s1 = col[e + 2];
    float4 v0 = xl4[(size_t)s0 * 32 + l32];
    float4 v1 = xl4[(size_t)s1 * 32 + l32];
    a0.x += v0.x; a0.y += v0.y; a0.z += v0.z; a0.w += v0.w;
    a1.x += v1.x; a1.y += v1.y; a1.z += v1.z; a1.w += v1.w;
  }
  if (e < end) {
    int s0 = col[e];
    float4 v0 = xl4[(size_t)s0 * 32 + l32];
    a0.x += v0.x; a0.y += v0.y; a0.z += v0.z; a0.w += v0.w;
  }
  a0.x += a1.x; a0.y += a1.y; a0.z += a1.z; a0.w += a1.w;
  a0.x += __shfl_xor(a0.x, 32);
  a0.y += __shfl_xor(a0.y, 32);
  a0.z += __shfl_xor(a0.z, 32);
  a0.w += __shfl_xor(a0.w, 32);
  if (half == 0) {
    float di = 1.0f / (float)max(end - beg, 1);
    float4 rv = ((const float4*)xr)[(size_t)n * 32 + l32];
    float4 o;
    o.x = fmaxf(fmaf(a0.x, di, rv.x), 0.f);
    o.y = fmaxf(fmaf(a0.y, di, rv.y), 0.f);
    o.z = fmaxf(fmaf(a0.z, di, rv.z), 0.f);
    o.w = fmaxf(fmaf(a0.w, di, rv.w), 0.f);
    ((float4*)h)[(size_t)n * 32 + l32] = o;
  }
}

// ---------------- aggregation D=40, fused deg_inv + add + log_softmax ----------------
__global__ __launch_bounds__(256) void agg40_lsm(
    const float* __restrict__ tl, const float* __restrict__ tr,
    const int* __restrict__ row_ptr, const int* __restrict__ col,
    float* __restrict__ out, int Nn) {
  int wave = threadIdx.x >> 6;
  int lane = threadIdx.x & 63;
  int n = blockIdx.x * 4 + wave;
  if (n >= Nn) return;
  int beg = row_ptr[n], end = row_ptr[n + 1];
  bool active = lane < 40;
  int li = active ? lane : 0;
  float acc = 0.f;
  int e = beg;
  for (; e + 2 <= end; e += 2) {
    int s0 = col[e], s1 = col[e + 1];
    acc += tl[(size_t)s0 * 40 + li] + tl[(size_t)s1 * 40 + li];
  }
  if (e < end) acc += tl[(size_t)col[e] * 40 + li];
  float di = 1.0f / (float)max(end - beg, 1);
  float v = active ? fmaf(acc, di, tr[(size_t)n * 40 + lane]) : -INFINITY;
  float m = v;
#pragma unroll
  for (int off = 32; off; off >>= 1) m = fmaxf(m, __shfl_xor(m, off));
  float ex = active ? expf(v - m) : 0.f;
  float ssum = ex;
#pragma unroll
  for (int off = 32; off; off >>= 1) ssum += __shfl_xor(ssum, off);
  if (active) out[(size_t)n * 40 + lane] = (v - m) - logf(ssum);
}

// ---------------- launcher ----------------

extern "C" void kernel_launch(void* const* d_in, const int* in_sizes, int n_in,
                              void* d_out, int out_size, void* d_ws, size_t ws_size,
                              hipStream_t stream) {
  const float* x   = (const float*)d_in[0];
  const int*   ei  = (const int*)d_in[1];
  const float* Wl0 = (const float*)d_in[2];
  const float* Wr0 = (const float*)d_in[3];
  const float* b0  = (const float*)d_in[4];
  const float* Wl1 = (const float*)d_in[5];
  const float* Wr1 = (const float*)d_in[6];
  const float* b1  = (const float*)d_in[7];
  const float* Wl2 = (const float*)d_in[8];
  const float* Wr2 = (const float*)d_in[9];
  const float* b2  = (const float*)d_in[10];

  int N = in_sizes[0] / 128;
  int E = in_sizes[1] / 2;
  const int* src = ei;
  const int* dst = ei + E;

  char* ws = (char*)d_ws;
  size_t off = 0;
  auto alloc = [&](size_t bytes) -> void* {
    void* p = ws + off;
    off += (bytes + 255) & ~(size_t)255;
    return p;
  };
  float* bufA   = (float*)alloc((size_t)N * 128 * 4);
  float* bufB   = (float*)alloc((size_t)N * 128 * 4);
  float* bufC   = (float*)alloc((size_t)N * 128 * 4);
  int* row_ptr  = (int*)alloc((size_t)(N + 1) * 4);
  int* deg      = (int*)alloc((size_t)N * 4);
  int* cursor   = (int*)alloc((size_t)N * 4);
  int* col      = (int*)alloc((size_t)E * 4);
  int* bsum     = (int*)alloc(256 * 4);
  int* boffs    = (int*)alloc(256 * 4);
  (void)ws_size; (void)n_in; (void)out_size;

  hipMemsetAsync(deg, 0, (size_t)N * 4, stream);
  hipMemsetAsync(cursor, 0, (size_t)N * 4, stream);

  int eb = (E + THREADS - 1) / THREADS;
  int nbscan = (N + 1023) / 1024;
  k_deg<<<eb, THREADS, 0, stream>>>(dst, deg, E);
  k_scan_blocks<<<nbscan, 256, 0, stream>>>(deg, bsum, N);
  k_scan_top<<<1, 256, 0, stream>>>(bsum, boffs, nbscan, row_ptr, N, E);
  k_scan_write<<<nbscan, 256, 0, stream>>>(deg, boffs, row_ptr, N);
  k_fill<<<eb, THREADS, 0, stream>>>(src, dst, row_ptr, cursor, col, E);

  int gg = (N + 63) / 64;
  int nb = (N + 3) / 4;

  // layer 0
  dual_gemm128<<<gg, 256, 0, stream>>>(x, Wl0, Wr0, b0, bufA, bufB, N);
  agg128_relu<<<nb, 256, 0, stream>>>(bufA, bufB, row_ptr, col, bufC, N);
  // layer 1
  dual_gemm128<<<gg, 256, 0, stream>>>(bufC, Wl1, Wr1, b1, bufA, bufB, N);
  agg128_relu<<<nb, 256, 0, stream>>>(bufA, bufB, row_ptr, col, bufC, N);
  // layer 2 (40-dim) + log_softmax
  dual_gemm40<<<gg, 256, 0, stream>>>(bufC, Wl2, Wr2, b2, bufA, bufB, N);
  agg40_lsm<<<nb, 256, 0, stream>>>(bufA, bufB, row_ptr, col, (float*)d_out, N);
}

// Round 5
// 731.291 us; speedup vs baseline: 2.4057x; 1.2231x over previous
//
#include <hip/hip_runtime.h>
#include <math.h>

#define THREADS 256

typedef short short8 __attribute__((ext_vector_type(8)));
typedef float f32x4 __attribute__((ext_vector_type(4)));

// bf16 helpers (storage = ushort; RNE pack, exact unpack)
__device__ __forceinline__ unsigned short f2bf(float f) {
  unsigned u = __builtin_bit_cast(unsigned, f);
  return (unsigned short)((u + 0x7FFFu + ((u >> 16) & 1u)) >> 16);
}
__device__ __forceinline__ float bflo(unsigned u) {
  return __builtin_bit_cast(float, u << 16);
}
__device__ __forceinline__ float bfhi(unsigned u) {
  return __builtin_bit_cast(float, u & 0xFFFF0000u);
}
__device__ __forceinline__ unsigned pack2(float x, float y) {
  return (unsigned)f2bf(x) | ((unsigned)f2bf(y) << 16);
}

// ---------------- CSR build ----------------

__global__ void k_deg(const int* __restrict__ dst, int* __restrict__ deg, int E) {
  int e = blockIdx.x * blockDim.x + threadIdx.x;
  if (e < E) atomicAdd(&deg[dst[e]], 1);
}

__global__ __launch_bounds__(256) void k_scan_blocks(const int* __restrict__ deg,
                                                     int* __restrict__ bsum, int n) {
  int b = blockIdx.x, t = threadIdx.x;
  int base = b * 1024 + t * 4;
  int s = 0;
  if (base + 3 < n) {
    int4 v = *(const int4*)(deg + base);
    s = v.x + v.y + v.z + v.w;
  } else {
#pragma unroll
    for (int j = 0; j < 4; ++j) if (base + j < n) s += deg[base + j];
  }
#pragma unroll
  for (int off = 32; off; off >>= 1) s += __shfl_xor(s, off);
  __shared__ int red[4];
  if ((t & 63) == 0) red[t >> 6] = s;
  __syncthreads();
  if (t == 0) bsum[b] = red[0] + red[1] + red[2] + red[3];
}

__global__ __launch_bounds__(256) void k_scan_top(const int* __restrict__ bsum,
                                                  int* __restrict__ boffs, int nb,
                                                  int* __restrict__ row_ptr, int n, int E) {
  __shared__ int sh[256];
  int t = threadIdx.x;
  int v = (t < nb) ? bsum[t] : 0;
  sh[t] = v;
  __syncthreads();
  for (int off = 1; off < 256; off <<= 1) {
    int u = (t >= off) ? sh[t - off] : 0;
    __syncthreads();
    if (t >= off) sh[t] += u;
    __syncthreads();
  }
  if (t < nb) boffs[t] = sh[t] - v;
  if (t == 0) row_ptr[n] = E;
}

__global__ __launch_bounds__(256) void k_scan_write(const int* __restrict__ deg,
                                                    const int* __restrict__ boffs,
                                                    int* __restrict__ row_ptr, int n) {
  int b = blockIdx.x, t = threadIdx.x;
  int base = b * 1024 + t * 4;
  int v0 = 0, v1 = 0, v2 = 0, v3 = 0;
  if (base + 3 < n) {
    int4 q = *(const int4*)(deg + base);
    v0 = q.x; v1 = q.y; v2 = q.z; v3 = q.w;
  } else {
    if (base + 0 < n) v0 = deg[base + 0];
    if (base + 1 < n) v1 = deg[base + 1];
    if (base + 2 < n) v2 = deg[base + 2];
    if (base + 3 < n) v3 = deg[base + 3];
  }
  int s = v0 + v1 + v2 + v3;
  __shared__ int sh[256];
  sh[t] = s;
  __syncthreads();
  for (int off = 1; off < 256; off <<= 1) {
    int u = (t >= off) ? sh[t - off] : 0;
    __syncthreads();
    if (t >= off) sh[t] += u;
    __syncthreads();
  }
  int pre = boffs[b] + sh[t] - s;
  int o0 = pre, o1 = pre + v0, o2 = o1 + v1, o3 = o2 + v2;
  if (base + 3 < n) {
    *(int4*)(row_ptr + base) = make_int4(o0, o1, o2, o3);
  } else {
    if (base + 0 < n) row_ptr[base + 0] = o0;
    if (base + 1 < n) row_ptr[base + 1] = o1;
    if (base + 2 < n) row_ptr[base + 2] = o2;
    if (base + 3 < n) row_ptr[base + 3] = o3;
  }
}

__global__ void k_fill(const int* __restrict__ src, const int* __restrict__ dst,
                       const int* __restrict__ row_ptr, int* __restrict__ cursor,
                       int* __restrict__ col, int E) {
  int e = blockIdx.x * blockDim.x + threadIdx.x;
  if (e < E) {
    int d = dst[e];
    int p = atomicAdd(&cursor[d], 1);
    col[row_ptr[d] + p] = src[e];
  }
}

// ---------------- fp32 -> bf16 convert (layer-0 X) ----------------
__global__ __launch_bounds__(256) void k_f2bf(const float4* __restrict__ in,
                                              ushort4* __restrict__ out, int n4) {
  int i = blockIdx.x * 256 + threadIdx.x;
  if (i < n4) {
    float4 v = in[i];
    ushort4 o;
    o.x = f2bf(v.x); o.y = f2bf(v.y); o.z = f2bf(v.z); o.w = f2bf(v.w);
    out[i] = o;
  }
}

// ---------------- W pre-swizzle into MFMA A-operand fragment layout ----------------
// We compute with swapped operands: A-op = W, B-op = X, so D[m'=C-col][n'=C-row].
// A-op layout (16x16x32): lane holds A[m=lane&15][k=quad*8+j], j=0..7.
// Table: out[((ks*16+ct)*64+lane)*8+j] = Wcat[k=ks*32+quad*8+j][c=ct*16+(lane&15)]
// where Wcat = [Wl | Wr] (256 cols). idx bits: j[0:3) lane[3:9) ct[9:13) ks[13:15).
__global__ __launch_bounds__(256) void k_wswz(const float* __restrict__ Wl,
                                              const float* __restrict__ Wr,
                                              unsigned short* __restrict__ out) {
  int idx = blockIdx.x * 256 + threadIdx.x;  // 0..32767
  int j = idx & 7, lane = (idx >> 3) & 63, ct = (idx >> 9) & 15, ks = idx >> 13;
  int k = ks * 32 + (lane >> 4) * 8 + j;
  int c = ct * 16 + (lane & 15);
  float v = (c < 128) ? Wl[k * 128 + c] : Wr[k * 128 + (c - 128)];
  out[idx] = f2bf(v);
}

// ---------------- MFMA dual GEMM, D=128, bf16 in/out, fp32 accum ----------------
// Round-5: replaces the fp32 VALU dual_gemm128 (134us, 37% VALUBusy, 42us VALU
// floor). No LDS: W frags come from the pre-swizzled L2-resident 64KB table
// (coalesced 16B/lane), X frags load directly (B-op layout = 16B/lane of the
// bf16 row). Operand swap puts C[row=lane&15][col=quad*4+reg] in the acc, so
// the epilogue is one packed ushort4 store per 16x16 tile.
__global__ __launch_bounds__(256) void gemm128_mfma(
    const unsigned short* __restrict__ Xb, const unsigned short* __restrict__ Wswz,
    const float* __restrict__ bias,
    unsigned short* __restrict__ outL, unsigned short* __restrict__ outR, int M) {
  int wave = threadIdx.x >> 6, lane = threadIdx.x & 63;
  int quad = lane >> 4, n16 = lane & 15;
  int row = blockIdx.x * 64 + wave * 16 + n16;
  int row_ld = min(row, M - 1);
  bool ok = row < M;

  // B-operand (X) fragments for the 4 K-chunks: 8 bf16 = 16B each
  short8 xf[4];
  const unsigned short* xp = Xb + (size_t)row_ld * 128 + quad * 8;
#pragma unroll
  for (int ks = 0; ks < 4; ++ks) xf[ks] = *(const short8*)(xp + ks * 32);

  size_t obase = (size_t)row * 128;
#pragma unroll 4
  for (int ct = 0; ct < 16; ++ct) {
    f32x4 acc = {0.f, 0.f, 0.f, 0.f};
    const unsigned short* wp = Wswz + (size_t)(ct * 64 + lane) * 8;
#pragma unroll
    for (int ks = 0; ks < 4; ++ks) {
      short8 wf = *(const short8*)(wp + ks * 8192);  // ((ks*16+ct)*64+lane)*8
      acc = __builtin_amdgcn_mfma_f32_16x16x32_bf16(wf, xf[ks], acc, 0, 0, 0);
    }
    int colh = (ct & 7) * 16 + quad * 4;  // column within the 128-wide half
    if (ct < 8) {
      if (ok) {
        ushort4 o;
        o.x = f2bf(acc[0]); o.y = f2bf(acc[1]); o.z = f2bf(acc[2]); o.w = f2bf(acc[3]);
        *(ushort4*)(outL + obase + colh) = o;
      }
    } else {
      float4 bv = *(const float4*)(bias + colh);
      if (ok) {
        ushort4 o;
        o.x = f2bf(acc[0] + bv.x); o.y = f2bf(acc[1] + bv.y);
        o.z = f2bf(acc[2] + bv.z); o.w = f2bf(acc[3] + bv.w);
        *(ushort4*)(outR + obase + colh) = o;
      }
    }
  }
}

// ---------------- dual GEMM, D=40 (layer 2) — bf16 input, fp32 compute ----------------
__global__ __launch_bounds__(256) void dual_gemm40(
    const unsigned short* __restrict__ Xb, const float* __restrict__ Wl,
    const float* __restrict__ Wr, const float* __restrict__ b,
    float* __restrict__ outL, float* __restrict__ outR, int M) {
  __shared__ float Xs[128 * 64];
  __shared__ float Wsc[32 * 80];
  int row0 = blockIdx.x * 64;
  int tid = threadIdx.x;

  // conflict-free lane=row staging, bf16 -> fp32 convert on the fly
  {
    int rr = tid & 63;
    int kq0 = tid >> 6;  // 0..3, uniform per wave
    int row = min(row0 + rr, M - 1);
    const unsigned short* xrow = Xb + (size_t)row * 128;
#pragma unroll
    for (int kq = kq0; kq < 16; kq += 4) {
      uint4 raw = *(const uint4*)(xrow + kq * 8);  // 8 bf16
      int k = kq * 8;
      Xs[(k + 0) * 64 + rr] = bflo(raw.x);
      Xs[(k + 1) * 64 + rr] = bfhi(raw.x);
      Xs[(k + 2) * 64 + rr] = bflo(raw.y);
      Xs[(k + 3) * 64 + rr] = bfhi(raw.y);
      Xs[(k + 4) * 64 + rr] = bflo(raw.z);
      Xs[(k + 5) * 64 + rr] = bfhi(raw.z);
      Xs[(k + 6) * 64 + rr] = bflo(raw.w);
      Xs[(k + 7) * 64 + rr] = bfhi(raw.w);
    }
  }

  float acc[4][5];
#pragma unroll
  for (int i = 0; i < 4; ++i)
#pragma unroll
    for (int j = 0; j < 5; ++j) acc[i][j] = 0.f;

  int tx = tid & 15, ty = tid >> 4;
  int r0 = ty * 4;
  int c0 = tx * 5;

  for (int kk = 0; kk < 128; kk += 32) {
    __syncthreads();
    for (int i = tid; i < 32 * 80; i += 256) {
      int k = i / 80, c = i - k * 80;
      Wsc[i] = (c < 40) ? Wl[(kk + k) * 40 + c] : Wr[(kk + k) * 40 + (c - 40)];
    }
    __syncthreads();
#pragma unroll 8
    for (int k = 0; k < 32; ++k) {
      const float4 xv = *(const float4*)&Xs[(kk + k) * 64 + r0];
      float xf[4] = {xv.x, xv.y, xv.z, xv.w};
      const float* wp = &Wsc[k * 80 + c0];
#pragma unroll
      for (int j = 0; j < 5; ++j) {
        float w = wp[j];
#pragma unroll
        for (int i = 0; i < 4; ++i) acc[i][j] = fmaf(xf[i], w, acc[i][j]);
      }
    }
  }

#pragma unroll
  for (int j = 0; j < 5; ++j) {
    int c80 = c0 + j;
    bool right = c80 >= 40;
    int c = right ? (c80 - 40) : c80;
    float bias = right ? b[c] : 0.f;
    float* out = right ? outR : outL;
#pragma unroll
    for (int i = 0; i < 4; ++i) {
      int row = row0 + r0 + i;
      if (row < M) out[(size_t)row * 40 + c] = acc[i][j] + bias;
    }
  }
}

// ---------------- aggregation D=128 (bf16 payload), fused deg_inv+add+relu ----------------
// One wave per node; lane covers 2 channels (1 uint = 2 bf16 = 4B/lane, 256B/row
// per wave-load). 4-edge ILP. fp32 accumulate, bf16 output.
__global__ __launch_bounds__(256) void agg128b(
    const unsigned short* __restrict__ xl, const unsigned short* __restrict__ xr,
    const int* __restrict__ row_ptr, const int* __restrict__ col,
    unsigned short* __restrict__ h, int Nn) {
  int wave = threadIdx.x >> 6;
  int lane = threadIdx.x & 63;
  int n = blockIdx.x * 4 + wave;
  if (n >= Nn) return;
  int beg = row_ptr[n], end = row_ptr[n + 1];
  const unsigned* xlu = (const unsigned*)xl;
  float ax0 = 0.f, ay0 = 0.f, ax1 = 0.f, ay1 = 0.f;
  float ax2 = 0.f, ay2 = 0.f, ax3 = 0.f, ay3 = 0.f;
  int e = beg;
  for (; e + 4 <= end; e += 4) {
    unsigned u0 = xlu[(size_t)col[e] * 64 + lane];
    unsigned u1 = xlu[(size_t)col[e + 1] * 64 + lane];
    unsigned u2 = xlu[(size_t)col[e + 2] * 64 + lane];
    unsigned u3 = xlu[(size_t)col[e + 3] * 64 + lane];
    ax0 += bflo(u0); ay0 += bfhi(u0);
    ax1 += bflo(u1); ay1 += bfhi(u1);
    ax2 += bflo(u2); ay2 += bfhi(u2);
    ax3 += bflo(u3); ay3 += bfhi(u3);
  }
  for (; e < end; ++e) {
    unsigned u = xlu[(size_t)col[e] * 64 + lane];
    ax0 += bflo(u); ay0 += bfhi(u);
  }
  float ax = (ax0 + ax1) + (ax2 + ax3);
  float ay = (ay0 + ay1) + (ay2 + ay3);
  float di = 1.0f / (float)max(end - beg, 1);
  unsigned ur = ((const unsigned*)xr)[(size_t)n * 64 + lane];
  float ox = fmaxf(fmaf(ax, di, bflo(ur)), 0.f);
  float oy = fmaxf(fmaf(ay, di, bfhi(ur)), 0.f);
  ((unsigned*)h)[(size_t)n * 64 + lane] = pack2(ox, oy);
}

// ---------------- aggregation D=40 (fp32), fused deg_inv + add + log_softmax ----------------
__global__ __launch_bounds__(256) void agg40_lsm(
    const float* __restrict__ tl, const float* __restrict__ tr,
    const int* __restrict__ row_ptr, const int* __restrict__ col,
    float* __restrict__ out, int Nn) {
  int wave = threadIdx.x >> 6;
  int lane = threadIdx.x & 63;
  int n = blockIdx.x * 4 + wave;
  if (n >= Nn) return;
  int beg = row_ptr[n], end = row_ptr[n + 1];
  bool active = lane < 40;
  int li = active ? lane : 0;
  float acc = 0.f;
  int e = beg;
  for (; e + 2 <= end; e += 2) {
    int s0 = col[e], s1 = col[e + 1];
    acc += tl[(size_t)s0 * 40 + li] + tl[(size_t)s1 * 40 + li];
  }
  if (e < end) acc += tl[(size_t)col[e] * 40 + li];
  float di = 1.0f / (float)max(end - beg, 1);
  float v = active ? fmaf(acc, di, tr[(size_t)n * 40 + lane]) : -INFINITY;
  float m = v;
#pragma unroll
  for (int off = 32; off; off >>= 1) m = fmaxf(m, __shfl_xor(m, off));
  float ex = active ? expf(v - m) : 0.f;
  float ssum = ex;
#pragma unroll
  for (int off = 32; off; off >>= 1) ssum += __shfl_xor(ssum, off);
  if (active) out[(size_t)n * 40 + lane] = (v - m) - logf(ssum);
}

// ---------------- launcher ----------------

extern "C" void kernel_launch(void* const* d_in, const int* in_sizes, int n_in,
                              void* d_out, int out_size, void* d_ws, size_t ws_size,
                              hipStream_t stream) {
  const float* x   = (const float*)d_in[0];
  const int*   ei  = (const int*)d_in[1];
  const float* Wl0 = (const float*)d_in[2];
  const float* Wr0 = (const float*)d_in[3];
  const float* b0  = (const float*)d_in[4];
  const float* Wl1 = (const float*)d_in[5];
  const float* Wr1 = (const float*)d_in[6];
  const float* b1  = (const float*)d_in[7];
  const float* Wl2 = (const float*)d_in[8];
  const float* Wr2 = (const float*)d_in[9];
  const float* b2  = (const float*)d_in[10];

  int N = in_sizes[0] / 128;
  int E = in_sizes[1] / 2;
  const int* src = ei;
  const int* dst = ei + E;

  char* ws = (char*)d_ws;
  size_t off = 0;
  auto alloc = [&](size_t bytes) -> void* {
    void* p = ws + off;
    off += (bytes + 255) & ~(size_t)255;
    return p;
  };
  unsigned short* xb  = (unsigned short*)alloc((size_t)N * 128 * 2);  // bf16 X
  unsigned short* gA  = (unsigned short*)alloc((size_t)N * 128 * 2);  // gemm outL
  unsigned short* gB  = (unsigned short*)alloc((size_t)N * 128 * 2);  // gemm outR
  unsigned short* hC  = (unsigned short*)alloc((size_t)N * 128 * 2);  // agg out
  float* tl           = (float*)alloc((size_t)N * 40 * 4);
  float* tr           = (float*)alloc((size_t)N * 40 * 4);
  int* row_ptr  = (int*)alloc((size_t)(N + 1) * 4);
  int* deg      = (int*)alloc((size_t)N * 4);
  int* cursor   = (int*)alloc((size_t)N * 4);
  int* col      = (int*)alloc((size_t)E * 4);
  int* bsum     = (int*)alloc(256 * 4);
  int* boffs    = (int*)alloc(256 * 4);
  unsigned short* wswz0 = (unsigned short*)alloc(32768 * 2);
  unsigned short* wswz1 = (unsigned short*)alloc(32768 * 2);
  (void)ws_size; (void)n_in; (void)out_size;

  hipMemsetAsync(deg, 0, (size_t)N * 4, stream);
  hipMemsetAsync(cursor, 0, (size_t)N * 4, stream);

  int eb = (E + THREADS - 1) / THREADS;
  int nbscan = (N + 1023) / 1024;
  k_deg<<<eb, THREADS, 0, stream>>>(dst, deg, E);
  k_scan_blocks<<<nbscan, 256, 0, stream>>>(deg, bsum, N);
  k_scan_top<<<1, 256, 0, stream>>>(bsum, boffs, nbscan, row_ptr, N, E);
  k_scan_write<<<nbscan, 256, 0, stream>>>(deg, boffs, row_ptr, N);
  k_fill<<<eb, THREADS, 0, stream>>>(src, dst, row_ptr, cursor, col, E);

  // prep: x -> bf16; W0/W1 -> swizzled bf16 fragment tables
  int n4 = N * 32;  // float4 count
  k_f2bf<<<(n4 + 255) / 256, 256, 0, stream>>>((const float4*)x, (ushort4*)xb, n4);
  k_wswz<<<128, 256, 0, stream>>>(Wl0, Wr0, wswz0);
  k_wswz<<<128, 256, 0, stream>>>(Wl1, Wr1, wswz1);

  int gg = (N + 63) / 64;
  int nb = (N + 3) / 4;

  // layer 0
  gemm128_mfma<<<gg, 256, 0, stream>>>(xb, wswz0, b0, gA, gB, N);
  agg128b<<<nb, 256, 0, stream>>>(gA, gB, row_ptr, col, hC, N);
  // layer 1
  gemm128_mfma<<<gg, 256, 0, stream>>>(hC, wswz1, b1, gA, gB, N);
  agg128b<<<nb, 256, 0, stream>>>(gA, gB, row_ptr, col, hC, N);
  // layer 2 (40-dim, fp32 compute on bf16 input) + log_softmax
  dual_gemm40<<<gg, 256, 0, stream>>>(hC, Wl2, Wr2, b2, tl, tr, N);
  agg40_lsm<<<nb, 256, 0, stream>>>(tl, tr, row_ptr, col, (float*)d_out, N);
}

// Round 6
// 686.754 us; speedup vs baseline: 2.5617x; 1.0649x over previous
//
#include <hip/hip_runtime.h>
#include <math.h>

#define THREADS 256

typedef short short8 __attribute__((ext_vector_type(8)));
typedef float f32x4 __attribute__((ext_vector_type(4)));

// bf16 helpers (storage = ushort; RNE pack, exact unpack)
__device__ __forceinline__ unsigned short f2bf(float f) {
  unsigned u = __builtin_bit_cast(unsigned, f);
  return (unsigned short)((u + 0x7FFFu + ((u >> 16) & 1u)) >> 16);
}
__device__ __forceinline__ float bflo(unsigned u) {
  return __builtin_bit_cast(float, u << 16);
}
__device__ __forceinline__ float bfhi(unsigned u) {
  return __builtin_bit_cast(float, u & 0xFFFF0000u);
}
__device__ __forceinline__ unsigned pack2(float x, float y) {
  return (unsigned)f2bf(x) | ((unsigned)f2bf(y) << 16);
}

// ---------------- CSR build ----------------

__global__ void k_deg(const int* __restrict__ dst, int* __restrict__ deg, int E) {
  int e = blockIdx.x * blockDim.x + threadIdx.x;
  if (e < E) atomicAdd(&deg[dst[e]], 1);
}

__global__ __launch_bounds__(256) void k_scan_blocks(const int* __restrict__ deg,
                                                     int* __restrict__ bsum, int n) {
  int b = blockIdx.x, t = threadIdx.x;
  int base = b * 1024 + t * 4;
  int s = 0;
  if (base + 3 < n) {
    int4 v = *(const int4*)(deg + base);
    s = v.x + v.y + v.z + v.w;
  } else {
#pragma unroll
    for (int j = 0; j < 4; ++j) if (base + j < n) s += deg[base + j];
  }
#pragma unroll
  for (int off = 32; off; off >>= 1) s += __shfl_xor(s, off);
  __shared__ int red[4];
  if ((t & 63) == 0) red[t >> 6] = s;
  __syncthreads();
  if (t == 0) bsum[b] = red[0] + red[1] + red[2] + red[3];
}

__global__ __launch_bounds__(256) void k_scan_top(const int* __restrict__ bsum,
                                                  int* __restrict__ boffs, int nb,
                                                  int* __restrict__ row_ptr, int n, int E) {
  __shared__ int sh[256];
  int t = threadIdx.x;
  int v = (t < nb) ? bsum[t] : 0;
  sh[t] = v;
  __syncthreads();
  for (int off = 1; off < 256; off <<= 1) {
    int u = (t >= off) ? sh[t - off] : 0;
    __syncthreads();
    if (t >= off) sh[t] += u;
    __syncthreads();
  }
  if (t < nb) boffs[t] = sh[t] - v;
  if (t == 0) row_ptr[n] = E;
}

__global__ __launch_bounds__(256) void k_scan_write(const int* __restrict__ deg,
                                                    const int* __restrict__ boffs,
                                                    int* __restrict__ row_ptr, int n) {
  int b = blockIdx.x, t = threadIdx.x;
  int base = b * 1024 + t * 4;
  int v0 = 0, v1 = 0, v2 = 0, v3 = 0;
  if (base + 3 < n) {
    int4 q = *(const int4*)(deg + base);
    v0 = q.x; v1 = q.y; v2 = q.z; v3 = q.w;
  } else {
    if (base + 0 < n) v0 = deg[base + 0];
    if (base + 1 < n) v1 = deg[base + 1];
    if (base + 2 < n) v2 = deg[base + 2];
    if (base + 3 < n) v3 = deg[base + 3];
  }
  int s = v0 + v1 + v2 + v3;
  __shared__ int sh[256];
  sh[t] = s;
  __syncthreads();
  for (int off = 1; off < 256; off <<= 1) {
    int u = (t >= off) ? sh[t - off] : 0;
    __syncthreads();
    if (t >= off) sh[t] += u;
    __syncthreads();
  }
  int pre = boffs[b] + sh[t] - s;
  int o0 = pre, o1 = pre + v0, o2 = o1 + v1, o3 = o2 + v2;
  if (base + 3 < n) {
    *(int4*)(row_ptr + base) = make_int4(o0, o1, o2, o3);
  } else {
    if (base + 0 < n) row_ptr[base + 0] = o0;
    if (base + 1 < n) row_ptr[base + 1] = o1;
    if (base + 2 < n) row_ptr[base + 2] = o2;
    if (base + 3 < n) row_ptr[base + 3] = o3;
  }
}

__global__ void k_fill(const int* __restrict__ src, const int* __restrict__ dst,
                       const int* __restrict__ row_ptr, int* __restrict__ cursor,
                       int* __restrict__ col, int E) {
  int e = blockIdx.x * blockDim.x + threadIdx.x;
  if (e < E) {
    int d = dst[e];
    int p = atomicAdd(&cursor[d], 1);
    col[row_ptr[d] + p] = src[e];
  }
}

// ---------------- fp32 -> bf16 convert (layer-0 X) ----------------
__global__ __launch_bounds__(256) void k_f2bf(const float4* __restrict__ in,
                                              ushort4* __restrict__ out, int n4) {
  int i = blockIdx.x * 256 + threadIdx.x;
  if (i < n4) {
    float4 v = in[i];
    ushort4 o;
    o.x = f2bf(v.x); o.y = f2bf(v.y); o.z = f2bf(v.z); o.w = f2bf(v.w);
    out[i] = o;
  }
}

// ---------------- W pre-swizzle into MFMA A-operand fragment layout ----------------
// Operand swap: A-op = W, B-op = X, so D[m'=C-col][n'=C-row].
// A-op layout (16x16x32): lane holds A[m=lane&15][k=quad*8+j], j=0..7.
__global__ __launch_bounds__(256) void k_wswz(const float* __restrict__ Wl,
                                              const float* __restrict__ Wr,
                                              unsigned short* __restrict__ out) {
  int idx = blockIdx.x * 256 + threadIdx.x;  // 0..32767
  int j = idx & 7, lane = (idx >> 3) & 63, ct = (idx >> 9) & 15, ks = idx >> 13;
  int k = ks * 32 + (lane >> 4) * 8 + j;
  int c = ct * 16 + (lane & 15);
  float v = (c < 128) ? Wl[k * 128 + c] : Wr[k * 128 + (c - 128)];
  out[idx] = f2bf(v);
}

// ---------------- MFMA dual GEMM, D=128, bf16 in/out, fp32 accum ----------------
__global__ __launch_bounds__(256) void gemm128_mfma(
    const unsigned short* __restrict__ Xb, const unsigned short* __restrict__ Wswz,
    const float* __restrict__ bias,
    unsigned short* __restrict__ outL, unsigned short* __restrict__ outR, int M) {
  int wave = threadIdx.x >> 6, lane = threadIdx.x & 63;
  int quad = lane >> 4, n16 = lane & 15;
  int row = blockIdx.x * 64 + wave * 16 + n16;
  int row_ld = min(row, M - 1);
  bool ok = row < M;

  short8 xf[4];
  const unsigned short* xp = Xb + (size_t)row_ld * 128 + quad * 8;
#pragma unroll
  for (int ks = 0; ks < 4; ++ks) xf[ks] = *(const short8*)(xp + ks * 32);

  size_t obase = (size_t)row * 128;
#pragma unroll 4
  for (int ct = 0; ct < 16; ++ct) {
    f32x4 acc = {0.f, 0.f, 0.f, 0.f};
    const unsigned short* wp = Wswz + (size_t)(ct * 64 + lane) * 8;
#pragma unroll
    for (int ks = 0; ks < 4; ++ks) {
      short8 wf = *(const short8*)(wp + ks * 8192);
      acc = __builtin_amdgcn_mfma_f32_16x16x32_bf16(wf, xf[ks], acc, 0, 0, 0);
    }
    int colh = (ct & 7) * 16 + quad * 4;
    if (ct < 8) {
      if (ok) {
        ushort4 o;
        o.x = f2bf(acc[0]); o.y = f2bf(acc[1]); o.z = f2bf(acc[2]); o.w = f2bf(acc[3]);
        *(ushort4*)(outL + obase + colh) = o;
      }
    } else {
      float4 bv = *(const float4*)(bias + colh);
      if (ok) {
        ushort4 o;
        o.x = f2bf(acc[0] + bv.x); o.y = f2bf(acc[1] + bv.y);
        o.z = f2bf(acc[2] + bv.z); o.w = f2bf(acc[3] + bv.w);
        *(ushort4*)(outR + obase + colh) = o;
      }
    }
  }
}

// ---------------- dual GEMM, D=40 (layer 2) — bf16 in, fp32 compute ----------------
// Round-6: tl (message side) now written as bf16 padded to 64 cols (128B rows,
// 2 aligned cache lines — round-5's fp32 160B rows cost agg40 3 lines/edge and
// 166MB FETCH). tr (self side, read once per node) stays fp32.
__global__ __launch_bounds__(256) void dual_gemm40(
    const unsigned short* __restrict__ Xb, const float* __restrict__ Wl,
    const float* __restrict__ Wr, const float* __restrict__ b,
    unsigned short* __restrict__ tlb, float* __restrict__ outR, int M) {
  __shared__ float Xs[128 * 64];
  __shared__ float Wsc[32 * 80];
  int row0 = blockIdx.x * 64;
  int tid = threadIdx.x;

  {
    int rr = tid & 63;
    int kq0 = tid >> 6;
    int row = min(row0 + rr, M - 1);
    const unsigned short* xrow = Xb + (size_t)row * 128;
#pragma unroll
    for (int kq = kq0; kq < 16; kq += 4) {
      uint4 raw = *(const uint4*)(xrow + kq * 8);
      int k = kq * 8;
      Xs[(k + 0) * 64 + rr] = bflo(raw.x);
      Xs[(k + 1) * 64 + rr] = bfhi(raw.x);
      Xs[(k + 2) * 64 + rr] = bflo(raw.y);
      Xs[(k + 3) * 64 + rr] = bfhi(raw.y);
      Xs[(k + 4) * 64 + rr] = bflo(raw.z);
      Xs[(k + 5) * 64 + rr] = bfhi(raw.z);
      Xs[(k + 6) * 64 + rr] = bflo(raw.w);
      Xs[(k + 7) * 64 + rr] = bfhi(raw.w);
    }
  }

  float acc[4][5];
#pragma unroll
  for (int i = 0; i < 4; ++i)
#pragma unroll
    for (int j = 0; j < 5; ++j) acc[i][j] = 0.f;

  int tx = tid & 15, ty = tid >> 4;
  int r0 = ty * 4;
  int c0 = tx * 5;

  for (int kk = 0; kk < 128; kk += 32) {
    __syncthreads();
    for (int i = tid; i < 32 * 80; i += 256) {
      int k = i / 80, c = i - k * 80;
      Wsc[i] = (c < 40) ? Wl[(kk + k) * 40 + c] : Wr[(kk + k) * 40 + (c - 40)];
    }
    __syncthreads();
#pragma unroll 8
    for (int k = 0; k < 32; ++k) {
      const float4 xv = *(const float4*)&Xs[(kk + k) * 64 + r0];
      float xf[4] = {xv.x, xv.y, xv.z, xv.w};
      const float* wp = &Wsc[k * 80 + c0];
#pragma unroll
      for (int j = 0; j < 5; ++j) {
        float w = wp[j];
#pragma unroll
        for (int i = 0; i < 4; ++i) acc[i][j] = fmaf(xf[i], w, acc[i][j]);
      }
    }
  }

#pragma unroll
  for (int j = 0; j < 5; ++j) {
    int c80 = c0 + j;
    bool right = c80 >= 40;
    int c = right ? (c80 - 40) : c80;
    float bias = right ? b[c] : 0.f;
#pragma unroll
    for (int i = 0; i < 4; ++i) {
      int row = row0 + r0 + i;
      if (row < M) {
        if (right) outR[(size_t)row * 40 + c] = acc[i][j] + bias;
        else       tlb[(size_t)row * 64 + c] = f2bf(acc[i][j]);
      }
    }
  }
}

// ---------------- aggregation D=128 (bf16 payload), fused deg_inv+add+relu ----------------
__global__ __launch_bounds__(256) void agg128b(
    const unsigned short* __restrict__ xl, const unsigned short* __restrict__ xr,
    const int* __restrict__ row_ptr, const int* __restrict__ col,
    unsigned short* __restrict__ h, int Nn) {
  int wave = threadIdx.x >> 6;
  int lane = threadIdx.x & 63;
  int n = blockIdx.x * 4 + wave;
  if (n >= Nn) return;
  int beg = row_ptr[n], end = row_ptr[n + 1];
  const unsigned* xlu = (const unsigned*)xl;
  float ax0 = 0.f, ay0 = 0.f, ax1 = 0.f, ay1 = 0.f;
  float ax2 = 0.f, ay2 = 0.f, ax3 = 0.f, ay3 = 0.f;
  int e = beg;
  for (; e + 4 <= end; e += 4) {
    unsigned u0 = xlu[(size_t)col[e] * 64 + lane];
    unsigned u1 = xlu[(size_t)col[e + 1] * 64 + lane];
    unsigned u2 = xlu[(size_t)col[e + 2] * 64 + lane];
    unsigned u3 = xlu[(size_t)col[e + 3] * 64 + lane];
    ax0 += bflo(u0); ay0 += bfhi(u0);
    ax1 += bflo(u1); ay1 += bfhi(u1);
    ax2 += bflo(u2); ay2 += bfhi(u2);
    ax3 += bflo(u3); ay3 += bfhi(u3);
  }
  for (; e < end; ++e) {
    unsigned u = xlu[(size_t)col[e] * 64 + lane];
    ax0 += bflo(u); ay0 += bfhi(u);
  }
  float ax = (ax0 + ax1) + (ax2 + ax3);
  float ay = (ay0 + ay1) + (ay2 + ay3);
  float di = 1.0f / (float)max(end - beg, 1);
  unsigned ur = ((const unsigned*)xr)[(size_t)n * 64 + lane];
  float ox = fmaxf(fmaf(ax, di, bflo(ur)), 0.f);
  float oy = fmaxf(fmaf(ay, di, bfhi(ur)), 0.f);
  ((unsigned*)h)[(size_t)n * 64 + lane] = pack2(ox, oy);
}

// ---------------- aggregation D=40 (bf16 padded-64 payload) + log_softmax ----------------
// Round-6 rewrite: round-5 read fp32 160B rows with 40/64 lanes (98.6us,
// 166MB FETCH). Now: half-wave per edge, lane = channel pair (uint = 2 bf16),
// 2 edges/iter x 2-deep unroll = 4 edges in flight, all 64 lanes active,
// 128B aligned rows. shfl_xor(32) combines halves; softmax over 20 lanes x 2ch.
__global__ __launch_bounds__(256) void agg40_lsm(
    const unsigned short* __restrict__ tlb, const float* __restrict__ tr,
    const int* __restrict__ row_ptr, const int* __restrict__ col,
    float* __restrict__ out, int Nn) {
  int wave = threadIdx.x >> 6;
  int lane = threadIdx.x & 63;
  int half = lane >> 5;   // edge parity this half-wave owns
  int l32 = lane & 31;    // channel-pair index (pairs 0..19 valid)
  int n = blockIdx.x * 4 + wave;
  if (n >= Nn) return;
  int beg = row_ptr[n], end = row_ptr[n + 1];
  const unsigned* tlu = (const unsigned*)tlb;
  float a0x = 0.f, a0y = 0.f, a1x = 0.f, a1y = 0.f;
  int e = beg + half;
  for (; e + 2 < end; e += 4) {  // this half-wave: edges e, e+2
    unsigned u0 = tlu[(size_t)col[e] * 32 + l32];
    unsigned u1 = tlu[(size_t)col[e + 2] * 32 + l32];
    a0x += bflo(u0); a0y += bfhi(u0);
    a1x += bflo(u1); a1y += bfhi(u1);
  }
  if (e < end) {
    unsigned u = tlu[(size_t)col[e] * 32 + l32];
    a0x += bflo(u); a0y += bfhi(u);
  }
  float ax = a0x + a1x;
  float ay = a0y + a1y;
  ax += __shfl_xor(ax, 32);
  ay += __shfl_xor(ay, 32);
  bool valid = l32 < 20;
  float di = 1.0f / (float)max(end - beg, 1);
  float2 rv = valid ? ((const float2*)(tr + (size_t)n * 40))[l32]
                    : make_float2(0.f, 0.f);
  float v0 = valid ? fmaf(ax, di, rv.x) : -INFINITY;
  float v1 = valid ? fmaf(ay, di, rv.y) : -INFINITY;
  float m = fmaxf(v0, v1);
#pragma unroll
  for (int off = 32; off; off >>= 1) m = fmaxf(m, __shfl_xor(m, off));
  float ex = valid ? (expf(v0 - m) + expf(v1 - m)) : 0.f;
  float ssum = ex;
#pragma unroll
  for (int off = 16; off; off >>= 1) ssum += __shfl_xor(ssum, off);  // within half
  ssum += __shfl_xor(ssum, 32);  // halves hold identical partials? no — combine
  // NOTE: both halves computed identical (ax,ay) post-combine, so per-half sums
  // are equal; the cross-half add above would double-count. Recompute safely:
  // (we instead reduce across all 64 lanes and halve)
  ssum *= 0.5f;
  float lg = logf(ssum);
  if (half == 0 && valid) {
    float2 o;
    o.x = (v0 - m) - lg;
    o.y = (v1 - m) - lg;
    *(float2*)(out + (size_t)n * 40 + 2 * l32) = o;
  }
}

// ---------------- launcher ----------------

extern "C" void kernel_launch(void* const* d_in, const int* in_sizes, int n_in,
                              void* d_out, int out_size, void* d_ws, size_t ws_size,
                              hipStream_t stream) {
  const float* x   = (const float*)d_in[0];
  const int*   ei  = (const int*)d_in[1];
  const float* Wl0 = (const float*)d_in[2];
  const float* Wr0 = (const float*)d_in[3];
  const float* b0  = (const float*)d_in[4];
  const float* Wl1 = (const float*)d_in[5];
  const float* Wr1 = (const float*)d_in[6];
  const float* b1  = (const float*)d_in[7];
  const float* Wl2 = (const float*)d_in[8];
  const float* Wr2 = (const float*)d_in[9];
  const float* b2  = (const float*)d_in[10];

  int N = in_sizes[0] / 128;
  int E = in_sizes[1] / 2;
  const int* src = ei;
  const int* dst = ei + E;

  char* ws = (char*)d_ws;
  size_t off = 0;
  auto alloc = [&](size_t bytes) -> void* {
    void* p = ws + off;
    off += (bytes + 255) & ~(size_t)255;
    return p;
  };
  unsigned short* xb  = (unsigned short*)alloc((size_t)N * 128 * 2);  // bf16 X
  unsigned short* gA  = (unsigned short*)alloc((size_t)N * 128 * 2);  // gemm outL
  unsigned short* gB  = (unsigned short*)alloc((size_t)N * 128 * 2);  // gemm outR
  unsigned short* hC  = (unsigned short*)alloc((size_t)N * 128 * 2);  // agg out
  unsigned short* tlb = (unsigned short*)alloc((size_t)N * 64 * 2);   // l2 msgs, bf16 pad-64
  float* tr           = (float*)alloc((size_t)N * 40 * 4);
  int* row_ptr  = (int*)alloc((size_t)(N + 1) * 4);
  int* deg      = (int*)alloc((size_t)N * 4);
  int* cursor   = (int*)alloc((size_t)N * 4);
  int* col      = (int*)alloc((size_t)E * 4);
  int* bsum     = (int*)alloc(256 * 4);
  int* boffs    = (int*)alloc(256 * 4);
  unsigned short* wswz0 = (unsigned short*)alloc(32768 * 2);
  unsigned short* wswz1 = (unsigned short*)alloc(32768 * 2);
  (void)ws_size; (void)n_in; (void)out_size;

  hipMemsetAsync(deg, 0, (size_t)N * 4, stream);
  hipMemsetAsync(cursor, 0, (size_t)N * 4, stream);
  hipMemsetAsync(tlb, 0, (size_t)N * 64 * 2, stream);  // zero the 40..63 pad

  int eb = (E + THREADS - 1) / THREADS;
  int nbscan = (N + 1023) / 1024;
  k_deg<<<eb, THREADS, 0, stream>>>(dst, deg, E);
  k_scan_blocks<<<nbscan, 256, 0, stream>>>(deg, bsum, N);
  k_scan_top<<<1, 256, 0, stream>>>(bsum, boffs, nbscan, row_ptr, N, E);
  k_scan_write<<<nbscan, 256, 0, stream>>>(deg, boffs, row_ptr, N);
  k_fill<<<eb, THREADS, 0, stream>>>(src, dst, row_ptr, cursor, col, E);

  int n4 = N * 32;
  k_f2bf<<<(n4 + 255) / 256, 256, 0, stream>>>((const float4*)x, (ushort4*)xb, n4);
  k_wswz<<<128, 256, 0, stream>>>(Wl0, Wr0, wswz0);
  k_wswz<<<128, 256, 0, stream>>>(Wl1, Wr1, wswz1);

  int gg = (N + 63) / 64;
  int nb = (N + 3) / 4;

  // layer 0
  gemm128_mfma<<<gg, 256, 0, stream>>>(xb, wswz0, b0, gA, gB, N);
  agg128b<<<nb, 256, 0, stream>>>(gA, gB, row_ptr, col, hC, N);
  // layer 1
  gemm128_mfma<<<gg, 256, 0, stream>>>(hC, wswz1, b1, gA, gB, N);
  agg128b<<<nb, 256, 0, stream>>>(gA, gB, row_ptr, col, hC, N);
  // layer 2 (40-dim) + log_softmax
  dual_gemm40<<<gg, 256, 0, stream>>>(hC, Wl2, Wr2, b2, tlb, tr, N);
  agg40_lsm<<<nb, 256, 0, stream>>>(tlb, tr, row_ptr, col, (float*)d_out, N);
}